// Round 1
// baseline (6385.150 us; speedup 1.0000x reference)
//
#include <hip/hip_runtime.h>
#include <hip/hip_bf16.h>

#define FEAT 256
#define HDIM 256
#define CDIM 64
#define THETA 0.5f

// ---------------- degree / dinv ----------------
__global__ __launch_bounds__(256) void deg_count(const int* __restrict__ e0, int E, int* deg) {
    int i = blockIdx.x * 256 + threadIdx.x;
    if (i < E) atomicAdd(&deg[e0[i]], 1);
}

__global__ __launch_bounds__(256) void make_dinv(const int* __restrict__ deg, float* __restrict__ dinv, int N) {
    int i = blockIdx.x * 256 + threadIdx.x;
    if (i < N) dinv[i] = rsqrtf((float)(deg[i] + 1));  // +1 self loop; always >=1
}

// ---------------- fp32 GEMM: out[M,256] = A[M,256] @ W[256,256] ----------------
__global__ __launch_bounds__(256) void gemm256(const float* __restrict__ A,
                                               const float* __restrict__ W,
                                               float* __restrict__ out, int M) {
    __shared__ float Wl[32][256];
    __shared__ float Al[64][40];  // pad to 40 floats (160B) keeps 16B alignment per row
    const int tid = threadIdx.x;
    const int m0 = blockIdx.x * 64;
    const int c0 = (tid & 63) * 4;
    const int r0 = (tid >> 6) * 16;
    float4 acc[16];
#pragma unroll
    for (int i = 0; i < 16; ++i) acc[i] = make_float4(0.f, 0.f, 0.f, 0.f);

    for (int k0 = 0; k0 < 256; k0 += 32) {
        // W chunk: rows k0..k0+31, all 256 cols (2048 float4)
#pragma unroll
        for (int i = 0; i < 8; ++i) {
            int j = i * 256 + tid;
            int kk = j >> 6;
            int c4 = (j & 63) * 4;
            float4 v = *(const float4*)&W[(size_t)(k0 + kk) * 256 + c4];
            *(float4*)&Wl[kk][c4] = v;
        }
        // A chunk: rows m0..m0+63, cols k0..k0+31 (512 float4)
#pragma unroll
        for (int i = 0; i < 2; ++i) {
            int j = i * 256 + tid;
            int r = j >> 3;
            int k4 = (j & 7) * 4;
            int row = m0 + r;
            float4 v = (row < M) ? *(const float4*)&A[(size_t)row * 256 + k0 + k4]
                                 : make_float4(0.f, 0.f, 0.f, 0.f);
            *(float4*)&Al[r][k4] = v;
        }
        __syncthreads();
#pragma unroll
        for (int kk = 0; kk < 32; kk += 4) {
            float4 w0 = *(float4*)&Wl[kk + 0][c0];
            float4 w1 = *(float4*)&Wl[kk + 1][c0];
            float4 w2 = *(float4*)&Wl[kk + 2][c0];
            float4 w3 = *(float4*)&Wl[kk + 3][c0];
#pragma unroll
            for (int i = 0; i < 16; ++i) {
                float4 a = *(float4*)&Al[r0 + i][kk];
                acc[i].x = fmaf(a.x, w0.x, acc[i].x);
                acc[i].y = fmaf(a.x, w0.y, acc[i].y);
                acc[i].z = fmaf(a.x, w0.z, acc[i].z);
                acc[i].w = fmaf(a.x, w0.w, acc[i].w);
                acc[i].x = fmaf(a.y, w1.x, acc[i].x);
                acc[i].y = fmaf(a.y, w1.y, acc[i].y);
                acc[i].z = fmaf(a.y, w1.z, acc[i].z);
                acc[i].w = fmaf(a.y, w1.w, acc[i].w);
                acc[i].x = fmaf(a.z, w2.x, acc[i].x);
                acc[i].y = fmaf(a.z, w2.y, acc[i].y);
                acc[i].z = fmaf(a.z, w2.z, acc[i].z);
                acc[i].w = fmaf(a.z, w2.w, acc[i].w);
                acc[i].x = fmaf(a.w, w3.x, acc[i].x);
                acc[i].y = fmaf(a.w, w3.y, acc[i].y);
                acc[i].z = fmaf(a.w, w3.z, acc[i].z);
                acc[i].w = fmaf(a.w, w3.w, acc[i].w);
            }
        }
        __syncthreads();
    }
#pragma unroll
    for (int i = 0; i < 16; ++i) {
        int row = m0 + r0 + i;
        if (row < M) *(float4*)&out[(size_t)row * 256 + c0] = acc[i];
    }
}

// ---------------- SpMM edge scatter: acc[row] += dinv[row]*dinv[col] * h[col] ----------------
__global__ __launch_bounds__(256) void spmm_scatter(const int* __restrict__ e0,
                                                    const int* __restrict__ e1,
                                                    const float* __restrict__ h,
                                                    const float* __restrict__ dinv,
                                                    float* acc, int E) {
    int gw = (blockIdx.x * 256 + threadIdx.x) >> 6;  // one wave per edge
    int lane = threadIdx.x & 63;
    if (gw >= E) return;
    int r = e0[gw];
    int c = e1[gw];
    float nw = dinv[r] * dinv[c];
    const float4 hv = *(const float4*)&h[(size_t)c * 256 + lane * 4];
    float* p = &acc[(size_t)r * 256 + lane * 4];
    unsafeAtomicAdd(p + 0, hv.x * nw);
    unsafeAtomicAdd(p + 1, hv.y * nw);
    unsafeAtomicAdd(p + 2, hv.z * nw);
    unsafeAtomicAdd(p + 3, hv.w * nw);
}

// ---------------- finalize: x = acc + dinv[i]^2 * h[i] + b  (+relu) ----------------
__global__ __launch_bounds__(256) void conv_finalize(float* __restrict__ x,
                                                     const float* __restrict__ h,
                                                     const float* __restrict__ dinv,
                                                     const float* __restrict__ bias,
                                                     int N, int do_relu) {
    int idx = blockIdx.x * 256 + threadIdx.x;  // over N*64 float4s
    if (idx >= N * 64) return;
    int row = idx >> 6;
    int f4 = (idx & 63) * 4;
    float di = dinv[row];
    float s = di * di;
    float4 a = *(float4*)&x[(size_t)idx * 4];
    float4 hv = *(const float4*)&h[(size_t)idx * 4];
    float4 bv = *(const float4*)&bias[f4];
    float4 r;
    r.x = a.x + s * hv.x + bv.x;
    r.y = a.y + s * hv.y + bv.y;
    r.z = a.z + s * hv.z + bv.z;
    r.w = a.w + s * hv.w + bv.w;
    if (do_relu) {
        r.x = fmaxf(r.x, 0.f);
        r.y = fmaxf(r.y, 0.f);
        r.z = fmaxf(r.z, 0.f);
        r.w = fmaxf(r.w, 0.f);
    }
    *(float4*)&x[(size_t)idx * 4] = r;
}

// ---------------- double L2 normalize, in place, one wave per row ----------------
__global__ __launch_bounds__(256) void l2norm2(float* __restrict__ rep, int N) {
    int gw = (blockIdx.x * 256 + threadIdx.x) >> 6;
    int lane = threadIdx.x & 63;
    if (gw >= N) return;
    float4 v = *(float4*)&rep[(size_t)gw * 256 + lane * 4];
    float ss = v.x * v.x + v.y * v.y + v.z * v.z + v.w * v.w;
#pragma unroll
    for (int o = 1; o < 64; o <<= 1) ss += __shfl_xor(ss, o);
    float inv = 1.0f / fmaxf(sqrtf(ss), 1e-12f);
    v.x *= inv; v.y *= inv; v.z *= inv; v.w *= inv;
    float ss2 = v.x * v.x + v.y * v.y + v.z * v.z + v.w * v.w;
#pragma unroll
    for (int o = 1; o < 64; o <<= 1) ss2 += __shfl_xor(ss2, o);
    float inv2 = 1.0f / fmaxf(sqrtf(ss2), 1e-12f);
    v.x *= inv2; v.y *= inv2; v.z *= inv2; v.w *= inv2;
    *(float4*)&rep[(size_t)gw * 256 + lane * 4] = v;
}

// ---------------- head GEMM: y[M,64] = rep[M,256] @ Wy[256,64] + by ----------------
// NOTE: out may be only 4B-aligned (starts 1 float after rep+rec in d_out) -> scalar stores.
__global__ __launch_bounds__(256) void gemm_wy(const float* __restrict__ A,
                                               const float* __restrict__ W,
                                               const float* __restrict__ bias,
                                               float* __restrict__ out, int M) {
    __shared__ float Wl[32][64];
    __shared__ float Al[64][40];
    const int tid = threadIdx.x;
    const int m0 = blockIdx.x * 64;
    const int c0 = (tid & 15) * 4;
    const int r0 = (tid >> 4) * 4;
    float4 acc[4];
#pragma unroll
    for (int i = 0; i < 4; ++i) acc[i] = make_float4(0.f, 0.f, 0.f, 0.f);

    for (int k0 = 0; k0 < 256; k0 += 32) {
#pragma unroll
        for (int i = 0; i < 2; ++i) {
            int j = i * 256 + tid;  // 0..511
            int kk = j >> 4;
            int c4 = (j & 15) * 4;
            float4 v = *(const float4*)&W[(size_t)(k0 + kk) * 64 + c4];
            *(float4*)&Wl[kk][c4] = v;
        }
#pragma unroll
        for (int i = 0; i < 2; ++i) {
            int j = i * 256 + tid;
            int r = j >> 3;
            int k4 = (j & 7) * 4;
            int row = m0 + r;
            float4 v = (row < M) ? *(const float4*)&A[(size_t)row * 256 + k0 + k4]
                                 : make_float4(0.f, 0.f, 0.f, 0.f);
            *(float4*)&Al[r][k4] = v;
        }
        __syncthreads();
#pragma unroll
        for (int kk = 0; kk < 32; kk += 4) {
            float4 w0 = *(float4*)&Wl[kk + 0][c0];
            float4 w1 = *(float4*)&Wl[kk + 1][c0];
            float4 w2 = *(float4*)&Wl[kk + 2][c0];
            float4 w3 = *(float4*)&Wl[kk + 3][c0];
#pragma unroll
            for (int i = 0; i < 4; ++i) {
                float4 a = *(float4*)&Al[r0 + i][kk];
                acc[i].x = fmaf(a.x, w0.x, acc[i].x);
                acc[i].y = fmaf(a.x, w0.y, acc[i].y);
                acc[i].z = fmaf(a.x, w0.z, acc[i].z);
                acc[i].w = fmaf(a.x, w0.w, acc[i].w);
                acc[i].x = fmaf(a.y, w1.x, acc[i].x);
                acc[i].y = fmaf(a.y, w1.y, acc[i].y);
                acc[i].z = fmaf(a.y, w1.z, acc[i].z);
                acc[i].w = fmaf(a.y, w1.w, acc[i].w);
                acc[i].x = fmaf(a.z, w2.x, acc[i].x);
                acc[i].y = fmaf(a.z, w2.y, acc[i].y);
                acc[i].z = fmaf(a.z, w2.z, acc[i].z);
                acc[i].w = fmaf(a.z, w2.w, acc[i].w);
                acc[i].x = fmaf(a.w, w3.x, acc[i].x);
                acc[i].y = fmaf(a.w, w3.y, acc[i].y);
                acc[i].z = fmaf(a.w, w3.z, acc[i].z);
                acc[i].w = fmaf(a.w, w3.w, acc[i].w);
            }
        }
        __syncthreads();
    }
    float4 bv = *(const float4*)&bias[c0];
#pragma unroll
    for (int i = 0; i < 4; ++i) {
        int row = m0 + r0 + i;
        if (row < M) {
            float* o = &out[(size_t)row * 64 + c0];
            o[0] = acc[i].x + bv.x;
            o[1] = acc[i].y + bv.y;
            o[2] = acc[i].z + bv.z;
            o[3] = acc[i].w + bv.w;
        }
    }
}

// ---------------- reconstruction loss ----------------
// accum[0]=pos_loss, accum[1]=neg_loss, accum[2]=n_pos, accum[3]=n_neg
__global__ __launch_bounds__(256) void loss_kernel(const int* __restrict__ e0,
                                                   const int* __restrict__ e1,
                                                   const int* __restrict__ n0,
                                                   const int* __restrict__ n1,
                                                   const float* __restrict__ rep,
                                                   const float* __restrict__ feat,
                                                   const float* __restrict__ ls,
                                                   float* accum, int E) {
    const int lane = threadIdx.x & 63;
    const int wline = threadIdx.x >> 6;
    const int gw = blockIdx.x * 4 + wline;
    const int nw = gridDim.x * 4;
    float ap = 0.f, an = 0.f, cp = 0.f, cn = 0.f;
    for (int e = gw; e < E; e += nw) {
        int a = e0[e], b = e1[e];
        const float4 ra = *(const float4*)&rep[(size_t)a * 256 + lane * 4];
        const float4 rb = *(const float4*)&rep[(size_t)b * 256 + lane * 4];
        float dp = ra.x * rb.x + ra.y * rb.y + ra.z * rb.z + ra.w * rb.w;
        const float4 fa = *(const float4*)&feat[(size_t)a * 256 + lane * 4];
        const float4 fb = *(const float4*)&feat[(size_t)b * 256 + lane * 4];
        float df = fa.x * fb.x + fa.y * fb.y + fa.z * fb.z + fa.w * fb.w;
        int c = n0[e], d = n1[e];
        const float4 rc = *(const float4*)&rep[(size_t)c * 256 + lane * 4];
        const float4 rd = *(const float4*)&rep[(size_t)d * 256 + lane * 4];
        float dn = rc.x * rd.x + rc.y * rd.y + rc.z * rd.z + rc.w * rd.w;
#pragma unroll
        for (int o = 1; o < 64; o <<= 1) {
            dp += __shfl_xor(dp, o);
            df += __shfl_xor(df, o);
            dn += __shfl_xor(dn, o);
        }
        if (lane == 0) {
            if (a < b) {
                float pw = fmaxf(dp, 0.f);
                float pos = THETA * df + (1.0f - THETA) * pw;
                float t = pos - ls[e];
                ap += t * t;
                cp += 1.f;
            }
            if (c < d) {
                float nwt = fmaxf(dn, 0.f);
                an += nwt * nwt;
                cn += 1.f;
            }
        }
    }
    __shared__ float s[4][4];
    if (lane == 0) {
        s[wline][0] = ap;
        s[wline][1] = an;
        s[wline][2] = cp;
        s[wline][3] = cn;
    }
    __syncthreads();
    if (threadIdx.x == 0) {
        float tp = 0.f, tn = 0.f, tcp = 0.f, tcn = 0.f;
#pragma unroll
        for (int w = 0; w < 4; ++w) {
            tp += s[w][0];
            tn += s[w][1];
            tcp += s[w][2];
            tcn += s[w][3];
        }
        unsafeAtomicAdd(&accum[0], tp);
        unsafeAtomicAdd(&accum[1], tn);
        unsafeAtomicAdd(&accum[2], tcp);
        unsafeAtomicAdd(&accum[3], tcn);
    }
}

__global__ void loss_final(const float* __restrict__ accum, float* __restrict__ out, int N) {
    out[0] = (accum[1] + accum[0]) * (float)N / (accum[3] + accum[2]);
}

// ---------------- launcher ----------------
extern "C" void kernel_launch(void* const* d_in, const int* in_sizes, int n_in,
                              void* d_out, int out_size, void* d_ws, size_t ws_size,
                              hipStream_t stream) {
    const int* edge = (const int*)d_in[0];
    const float* features = (const float*)d_in[1];
    const float* ls = (const float*)d_in[2];
    const int* nedge = (const int*)d_in[3];
    const float* W1 = (const float*)d_in[4];
    const float* b1 = (const float*)d_in[5];
    const float* W2 = (const float*)d_in[6];
    const float* b2 = (const float*)d_in[7];
    const float* Wy = (const float*)d_in[8];
    const float* by = (const float*)d_in[9];

    const int E = in_sizes[0] / 2;
    const int N = in_sizes[1] / FEAT;
    const int* e0 = edge;
    const int* e1 = edge + E;
    const int* n0 = nedge;
    const int* n1 = nedge + E;

    float* rep = (float*)d_out;                    // [N,256]
    float* rec = rep + (size_t)N * 256;            // scalar
    float* y = rec + 1;                            // [N,64], 4B-aligned only

    // workspace carve-out
    char* base = (char*)d_ws;
    size_t off = 0;
    auto carve = [&](size_t bytes) -> void* {
        void* p = base + off;
        off += (bytes + 1023) & ~(size_t)1023;
        return p;
    };
    int* deg = (int*)carve((size_t)N * 4);
    float* dinv = (float*)carve((size_t)N * 4);
    float* accum = (float*)carve(16);
    float* bufA = (float*)carve((size_t)N * 256 * 4);
    float* bufB = (float*)carve((size_t)N * 256 * 4);

    // degrees
    hipMemsetAsync(deg, 0, (size_t)N * 4, stream);
    deg_count<<<(E + 255) / 256, 256, 0, stream>>>(e0, E, deg);
    make_dinv<<<(N + 255) / 256, 256, 0, stream>>>(deg, dinv, N);

    const int gblk = (N + 63) / 64;

    // conv1: h1 = features @ W1 ; x1 = relu(spmm(h1) + selfloop + b1)
    gemm256<<<gblk, 256, 0, stream>>>(features, W1, bufA, N);
    hipMemsetAsync(bufB, 0, (size_t)N * 256 * 4, stream);
    spmm_scatter<<<(E + 3) / 4, 256, 0, stream>>>(e0, e1, bufA, dinv, bufB, E);
    conv_finalize<<<(N * 64 + 255) / 256, 256, 0, stream>>>(bufB, bufA, dinv, b1, N, 1);

    // conv2: h2 = x1 @ W2 ; x2 = spmm(h2) + selfloop + b2 (accumulated directly into rep)
    gemm256<<<gblk, 256, 0, stream>>>(bufB, W2, bufA, N);
    hipMemsetAsync(rep, 0, (size_t)N * 256 * 4, stream);
    spmm_scatter<<<(E + 3) / 4, 256, 0, stream>>>(e0, e1, bufA, dinv, rep, E);
    conv_finalize<<<(N * 64 + 255) / 256, 256, 0, stream>>>(rep, bufA, dinv, b2, N, 0);

    // rep = l2norm(l2norm(x2))
    l2norm2<<<(N + 3) / 4, 256, 0, stream>>>(rep, N);

    // y = rep @ Wy + by
    gemm_wy<<<gblk, 256, 0, stream>>>(rep, Wy, by, y, N);

    // loss
    hipMemsetAsync(accum, 0, 16, stream);
    loss_kernel<<<2048, 256, 0, stream>>>(e0, e1, n0, n1, rep, features, ls, accum, E);
    loss_final<<<1, 1, 0, stream>>>(accum, rec, N);
}

// Round 2
// 1417.919 us; speedup vs baseline: 4.5032x; 4.5032x over previous
//
#include <hip/hip_runtime.h>
#include <hip/hip_bf16.h>

#define FEAT 256
#define HDIM 256
#define CDIM 64
#define THETA 0.5f

// ---------------- degree ----------------
__global__ __launch_bounds__(256) void deg_count(const int* __restrict__ e0, int E, int* deg) {
    int i = blockIdx.x * 256 + threadIdx.x;
    if (i < E) atomicAdd(&deg[e0[i]], 1);
}

__global__ __launch_bounds__(256) void make_dinv(const int* __restrict__ deg, float* __restrict__ dinv, int N) {
    int i = blockIdx.x * 256 + threadIdx.x;
    if (i < N) dinv[i] = rsqrtf((float)(deg[i] + 1));  // +1 self loop
}

// ---------------- single-block exclusive scan -> rowptr, cursor ----------------
__global__ __launch_bounds__(256) void scan_rowptr(const int* __restrict__ deg,
                                                   int* __restrict__ rowptr,
                                                   int* __restrict__ cursor, int N) {
    __shared__ int part[256];
    const int tid = threadIdx.x;
    const int chunk = (N + 255) / 256;
    const int s = tid * chunk;
    const int e = min(s + chunk, N);
    int sum = 0;
    for (int i = s; i < e; ++i) sum += deg[i];
    part[tid] = sum;
    __syncthreads();
#pragma unroll
    for (int off = 1; off < 256; off <<= 1) {
        int t = (tid >= off) ? part[tid - off] : 0;
        __syncthreads();
        part[tid] += t;
        __syncthreads();
    }
    int run = part[tid] - sum;  // exclusive prefix
    for (int i = s; i < e; ++i) {
        rowptr[i] = run;
        cursor[i] = run;
        run += deg[i];
    }
    if (tid == 255) rowptr[N] = run;
}

// ---------------- bucket edges into CSR (col only; weights recomputed later) ----------------
__global__ __launch_bounds__(256) void bucket_edges(const int* __restrict__ e0,
                                                    const int* __restrict__ e1,
                                                    int* cursor, int* __restrict__ colIdx, int E) {
    int i = blockIdx.x * 256 + threadIdx.x;
    if (i < E) {
        int r = e0[i];
        int pos = atomicAdd(&cursor[r], 1);
        colIdx[pos] = e1[i];
    }
}

// ---------------- fp32 GEMM: out[M,256] = A[M,256] @ W[256,256] ----------------
__global__ __launch_bounds__(256) void gemm256(const float* __restrict__ A,
                                               const float* __restrict__ W,
                                               float* __restrict__ out, int M) {
    __shared__ float Wl[32][256];
    __shared__ float Al[64][40];
    const int tid = threadIdx.x;
    const int m0 = blockIdx.x * 64;
    const int c0 = (tid & 63) * 4;
    const int r0 = (tid >> 6) * 16;
    float4 acc[16];
#pragma unroll
    for (int i = 0; i < 16; ++i) acc[i] = make_float4(0.f, 0.f, 0.f, 0.f);

    for (int k0 = 0; k0 < 256; k0 += 32) {
#pragma unroll
        for (int i = 0; i < 8; ++i) {
            int j = i * 256 + tid;
            int kk = j >> 6;
            int c4 = (j & 63) * 4;
            float4 v = *(const float4*)&W[(size_t)(k0 + kk) * 256 + c4];
            *(float4*)&Wl[kk][c4] = v;
        }
#pragma unroll
        for (int i = 0; i < 2; ++i) {
            int j = i * 256 + tid;
            int r = j >> 3;
            int k4 = (j & 7) * 4;
            int row = m0 + r;
            float4 v = (row < M) ? *(const float4*)&A[(size_t)row * 256 + k0 + k4]
                                 : make_float4(0.f, 0.f, 0.f, 0.f);
            *(float4*)&Al[r][k4] = v;
        }
        __syncthreads();
#pragma unroll
        for (int kk = 0; kk < 32; kk += 4) {
            float4 w0 = *(float4*)&Wl[kk + 0][c0];
            float4 w1 = *(float4*)&Wl[kk + 1][c0];
            float4 w2 = *(float4*)&Wl[kk + 2][c0];
            float4 w3 = *(float4*)&Wl[kk + 3][c0];
#pragma unroll
            for (int i = 0; i < 16; ++i) {
                float4 a = *(float4*)&Al[r0 + i][kk];
                acc[i].x = fmaf(a.x, w0.x, acc[i].x);
                acc[i].y = fmaf(a.x, w0.y, acc[i].y);
                acc[i].z = fmaf(a.x, w0.z, acc[i].z);
                acc[i].w = fmaf(a.x, w0.w, acc[i].w);
                acc[i].x = fmaf(a.y, w1.x, acc[i].x);
                acc[i].y = fmaf(a.y, w1.y, acc[i].y);
                acc[i].z = fmaf(a.y, w1.z, acc[i].z);
                acc[i].w = fmaf(a.y, w1.w, acc[i].w);
                acc[i].x = fmaf(a.z, w2.x, acc[i].x);
                acc[i].y = fmaf(a.z, w2.y, acc[i].y);
                acc[i].z = fmaf(a.z, w2.z, acc[i].z);
                acc[i].w = fmaf(a.z, w2.w, acc[i].w);
                acc[i].x = fmaf(a.w, w3.x, acc[i].x);
                acc[i].y = fmaf(a.w, w3.y, acc[i].y);
                acc[i].z = fmaf(a.w, w3.z, acc[i].z);
                acc[i].w = fmaf(a.w, w3.w, acc[i].w);
            }
        }
        __syncthreads();
    }
#pragma unroll
    for (int i = 0; i < 16; ++i) {
        int row = m0 + r0 + i;
        if (row < M) *(float4*)&out[(size_t)row * 256 + c0] = acc[i];
    }
}

// ---------------- CSR gather SpMM fused with finalize ----------------
// out[row] = dinv[row] * sum_j dinv[col_j]*h[col_j] + dinv[row]^2 * h[row] + bias  (+relu)
__global__ __launch_bounds__(256) void spmm_gather(const int* __restrict__ rowptr,
                                                   const int* __restrict__ colIdx,
                                                   const float* __restrict__ h,
                                                   const float* __restrict__ dinv,
                                                   const float* __restrict__ bias,
                                                   float* __restrict__ out,
                                                   int N, int do_relu) {
    int row = (blockIdx.x * 256 + threadIdx.x) >> 6;
    int lane = threadIdx.x & 63;
    if (row >= N) return;
    int beg = rowptr[row];
    int end = rowptr[row + 1];
    float4 acc = make_float4(0.f, 0.f, 0.f, 0.f);
    int j = beg;
    for (; j + 3 < end; j += 4) {
        int c0 = colIdx[j + 0];
        int c1 = colIdx[j + 1];
        int c2 = colIdx[j + 2];
        int c3 = colIdx[j + 3];
        float w0 = dinv[c0], w1 = dinv[c1], w2 = dinv[c2], w3 = dinv[c3];
        float4 h0 = *(const float4*)&h[(size_t)c0 * 256 + lane * 4];
        float4 h1 = *(const float4*)&h[(size_t)c1 * 256 + lane * 4];
        float4 h2 = *(const float4*)&h[(size_t)c2 * 256 + lane * 4];
        float4 h3 = *(const float4*)&h[(size_t)c3 * 256 + lane * 4];
        acc.x = fmaf(w0, h0.x, acc.x); acc.y = fmaf(w0, h0.y, acc.y);
        acc.z = fmaf(w0, h0.z, acc.z); acc.w = fmaf(w0, h0.w, acc.w);
        acc.x = fmaf(w1, h1.x, acc.x); acc.y = fmaf(w1, h1.y, acc.y);
        acc.z = fmaf(w1, h1.z, acc.z); acc.w = fmaf(w1, h1.w, acc.w);
        acc.x = fmaf(w2, h2.x, acc.x); acc.y = fmaf(w2, h2.y, acc.y);
        acc.z = fmaf(w2, h2.z, acc.z); acc.w = fmaf(w2, h2.w, acc.w);
        acc.x = fmaf(w3, h3.x, acc.x); acc.y = fmaf(w3, h3.y, acc.y);
        acc.z = fmaf(w3, h3.z, acc.z); acc.w = fmaf(w3, h3.w, acc.w);
    }
    for (; j < end; ++j) {
        int c = colIdx[j];
        float w = dinv[c];
        float4 hv = *(const float4*)&h[(size_t)c * 256 + lane * 4];
        acc.x = fmaf(w, hv.x, acc.x); acc.y = fmaf(w, hv.y, acc.y);
        acc.z = fmaf(w, hv.z, acc.z); acc.w = fmaf(w, hv.w, acc.w);
    }
    float di = dinv[row];
    float s = di * di;
    float4 hv = *(const float4*)&h[(size_t)row * 256 + lane * 4];
    float4 bv = *(const float4*)&bias[lane * 4];
    float4 r;
    r.x = fmaf(di, acc.x, fmaf(s, hv.x, bv.x));
    r.y = fmaf(di, acc.y, fmaf(s, hv.y, bv.y));
    r.z = fmaf(di, acc.z, fmaf(s, hv.z, bv.z));
    r.w = fmaf(di, acc.w, fmaf(s, hv.w, bv.w));
    if (do_relu) {
        r.x = fmaxf(r.x, 0.f);
        r.y = fmaxf(r.y, 0.f);
        r.z = fmaxf(r.z, 0.f);
        r.w = fmaxf(r.w, 0.f);
    }
    *(float4*)&out[(size_t)row * 256 + lane * 4] = r;
}

// ---------------- double L2 normalize, in place, one wave per row ----------------
__global__ __launch_bounds__(256) void l2norm2(float* __restrict__ rep, int N) {
    int gw = (blockIdx.x * 256 + threadIdx.x) >> 6;
    int lane = threadIdx.x & 63;
    if (gw >= N) return;
    float4 v = *(float4*)&rep[(size_t)gw * 256 + lane * 4];
    float ss = v.x * v.x + v.y * v.y + v.z * v.z + v.w * v.w;
#pragma unroll
    for (int o = 1; o < 64; o <<= 1) ss += __shfl_xor(ss, o);
    float inv = 1.0f / fmaxf(sqrtf(ss), 1e-12f);
    v.x *= inv; v.y *= inv; v.z *= inv; v.w *= inv;
    float ss2 = v.x * v.x + v.y * v.y + v.z * v.z + v.w * v.w;
#pragma unroll
    for (int o = 1; o < 64; o <<= 1) ss2 += __shfl_xor(ss2, o);
    float inv2 = 1.0f / fmaxf(sqrtf(ss2), 1e-12f);
    v.x *= inv2; v.y *= inv2; v.z *= inv2; v.w *= inv2;
    *(float4*)&rep[(size_t)gw * 256 + lane * 4] = v;
}

// ---------------- head GEMM: y[M,64] = rep[M,256] @ Wy[256,64] + by ----------------
__global__ __launch_bounds__(256) void gemm_wy(const float* __restrict__ A,
                                               const float* __restrict__ W,
                                               const float* __restrict__ bias,
                                               float* __restrict__ out, int M) {
    __shared__ float Wl[32][64];
    __shared__ float Al[64][40];
    const int tid = threadIdx.x;
    const int m0 = blockIdx.x * 64;
    const int c0 = (tid & 15) * 4;
    const int r0 = (tid >> 4) * 4;
    float4 acc[4];
#pragma unroll
    for (int i = 0; i < 4; ++i) acc[i] = make_float4(0.f, 0.f, 0.f, 0.f);

    for (int k0 = 0; k0 < 256; k0 += 32) {
#pragma unroll
        for (int i = 0; i < 2; ++i) {
            int j = i * 256 + tid;
            int kk = j >> 4;
            int c4 = (j & 15) * 4;
            float4 v = *(const float4*)&W[(size_t)(k0 + kk) * 64 + c4];
            *(float4*)&Wl[kk][c4] = v;
        }
#pragma unroll
        for (int i = 0; i < 2; ++i) {
            int j = i * 256 + tid;
            int r = j >> 3;
            int k4 = (j & 7) * 4;
            int row = m0 + r;
            float4 v = (row < M) ? *(const float4*)&A[(size_t)row * 256 + k0 + k4]
                                 : make_float4(0.f, 0.f, 0.f, 0.f);
            *(float4*)&Al[r][k4] = v;
        }
        __syncthreads();
#pragma unroll
        for (int kk = 0; kk < 32; kk += 4) {
            float4 w0 = *(float4*)&Wl[kk + 0][c0];
            float4 w1 = *(float4*)&Wl[kk + 1][c0];
            float4 w2 = *(float4*)&Wl[kk + 2][c0];
            float4 w3 = *(float4*)&Wl[kk + 3][c0];
#pragma unroll
            for (int i = 0; i < 4; ++i) {
                float4 a = *(float4*)&Al[r0 + i][kk];
                acc[i].x = fmaf(a.x, w0.x, acc[i].x);
                acc[i].y = fmaf(a.x, w0.y, acc[i].y);
                acc[i].z = fmaf(a.x, w0.z, acc[i].z);
                acc[i].w = fmaf(a.x, w0.w, acc[i].w);
                acc[i].x = fmaf(a.y, w1.x, acc[i].x);
                acc[i].y = fmaf(a.y, w1.y, acc[i].y);
                acc[i].z = fmaf(a.y, w1.z, acc[i].z);
                acc[i].w = fmaf(a.y, w1.w, acc[i].w);
                acc[i].x = fmaf(a.z, w2.x, acc[i].x);
                acc[i].y = fmaf(a.z, w2.y, acc[i].y);
                acc[i].z = fmaf(a.z, w2.z, acc[i].z);
                acc[i].w = fmaf(a.z, w2.w, acc[i].w);
                acc[i].x = fmaf(a.w, w3.x, acc[i].x);
                acc[i].y = fmaf(a.w, w3.y, acc[i].y);
                acc[i].z = fmaf(a.w, w3.z, acc[i].z);
                acc[i].w = fmaf(a.w, w3.w, acc[i].w);
            }
        }
        __syncthreads();
    }
    float4 bv = *(const float4*)&bias[c0];
#pragma unroll
    for (int i = 0; i < 4; ++i) {
        int row = m0 + r0 + i;
        if (row < M) {
            float* o = &out[(size_t)row * 64 + c0];
            o[0] = acc[i].x + bv.x;
            o[1] = acc[i].y + bv.y;
            o[2] = acc[i].z + bv.z;
            o[3] = acc[i].w + bv.w;
        }
    }
}

// ---------------- reconstruction loss ----------------
__global__ __launch_bounds__(256) void loss_kernel(const int* __restrict__ e0,
                                                   const int* __restrict__ e1,
                                                   const int* __restrict__ n0,
                                                   const int* __restrict__ n1,
                                                   const float* __restrict__ rep,
                                                   const float* __restrict__ feat,
                                                   const float* __restrict__ ls,
                                                   float* accum, int E) {
    const int lane = threadIdx.x & 63;
    const int wline = threadIdx.x >> 6;
    const int gw = blockIdx.x * 4 + wline;
    const int nw = gridDim.x * 4;
    float ap = 0.f, an = 0.f, cp = 0.f, cn = 0.f;
    for (int e = gw; e < E; e += nw) {
        int a = e0[e], b = e1[e];
        const float4 ra = *(const float4*)&rep[(size_t)a * 256 + lane * 4];
        const float4 rb = *(const float4*)&rep[(size_t)b * 256 + lane * 4];
        float dp = ra.x * rb.x + ra.y * rb.y + ra.z * rb.z + ra.w * rb.w;
        const float4 fa = *(const float4*)&feat[(size_t)a * 256 + lane * 4];
        const float4 fb = *(const float4*)&feat[(size_t)b * 256 + lane * 4];
        float df = fa.x * fb.x + fa.y * fb.y + fa.z * fb.z + fa.w * fb.w;
        int c = n0[e], d = n1[e];
        const float4 rc = *(const float4*)&rep[(size_t)c * 256 + lane * 4];
        const float4 rd = *(const float4*)&rep[(size_t)d * 256 + lane * 4];
        float dn = rc.x * rd.x + rc.y * rd.y + rc.z * rd.z + rc.w * rd.w;
#pragma unroll
        for (int o = 1; o < 64; o <<= 1) {
            dp += __shfl_xor(dp, o);
            df += __shfl_xor(df, o);
            dn += __shfl_xor(dn, o);
        }
        if (lane == 0) {
            if (a < b) {
                float pw = fmaxf(dp, 0.f);
                float pos = THETA * df + (1.0f - THETA) * pw;
                float t = pos - ls[e];
                ap += t * t;
                cp += 1.f;
            }
            if (c < d) {
                float nwt = fmaxf(dn, 0.f);
                an += nwt * nwt;
                cn += 1.f;
            }
        }
    }
    __shared__ float s[4][4];
    if (lane == 0) {
        s[wline][0] = ap;
        s[wline][1] = an;
        s[wline][2] = cp;
        s[wline][3] = cn;
    }
    __syncthreads();
    if (threadIdx.x == 0) {
        float tp = 0.f, tn = 0.f, tcp = 0.f, tcn = 0.f;
#pragma unroll
        for (int w = 0; w < 4; ++w) {
            tp += s[w][0];
            tn += s[w][1];
            tcp += s[w][2];
            tcn += s[w][3];
        }
        unsafeAtomicAdd(&accum[0], tp);
        unsafeAtomicAdd(&accum[1], tn);
        unsafeAtomicAdd(&accum[2], tcp);
        unsafeAtomicAdd(&accum[3], tcn);
    }
}

__global__ void loss_final(const float* __restrict__ accum, float* __restrict__ out, int N) {
    out[0] = (accum[1] + accum[0]) * (float)N / (accum[3] + accum[2]);
}

// ---------------- launcher ----------------
extern "C" void kernel_launch(void* const* d_in, const int* in_sizes, int n_in,
                              void* d_out, int out_size, void* d_ws, size_t ws_size,
                              hipStream_t stream) {
    const int* edge = (const int*)d_in[0];
    const float* features = (const float*)d_in[1];
    const float* ls = (const float*)d_in[2];
    const int* nedge = (const int*)d_in[3];
    const float* W1 = (const float*)d_in[4];
    const float* b1 = (const float*)d_in[5];
    const float* W2 = (const float*)d_in[6];
    const float* b2 = (const float*)d_in[7];
    const float* Wy = (const float*)d_in[8];
    const float* by = (const float*)d_in[9];

    const int E = in_sizes[0] / 2;
    const int N = in_sizes[1] / FEAT;
    const int* e0 = edge;
    const int* e1 = edge + E;
    const int* n0 = nedge;
    const int* n1 = nedge + E;

    float* rep = (float*)d_out;          // [N,256] — also used as x1/x2 staging
    float* rec = rep + (size_t)N * 256;  // scalar
    float* y = rec + 1;                  // [N,64], 4B-aligned only

    // workspace carve-out (~55 MB)
    char* base = (char*)d_ws;
    size_t off = 0;
    auto carve = [&](size_t bytes) -> void* {
        void* p = base + off;
        off += (bytes + 1023) & ~(size_t)1023;
        return p;
    };
    int* deg = (int*)carve((size_t)N * 4);
    float* dinv = (float*)carve((size_t)N * 4);
    float* accum = (float*)carve(16);
    int* rowptr = (int*)carve((size_t)(N + 1) * 4);
    int* cursor = (int*)carve((size_t)N * 4);
    int* colIdx = (int*)carve((size_t)E * 4);
    float* bufA = (float*)carve((size_t)N * 256 * 4);

    // CSR build
    hipMemsetAsync(deg, 0, (size_t)N * 4, stream);
    deg_count<<<(E + 255) / 256, 256, 0, stream>>>(e0, E, deg);
    make_dinv<<<(N + 255) / 256, 256, 0, stream>>>(deg, dinv, N);
    scan_rowptr<<<1, 256, 0, stream>>>(deg, rowptr, cursor, N);
    bucket_edges<<<(E + 255) / 256, 256, 0, stream>>>(e0, e1, cursor, colIdx, E);

    const int gblk = (N + 63) / 64;
    const int wblk = (N + 3) / 4;

    // conv1: h1 = features @ W1 (bufA); x1 = relu(gather + selfloop + b1) -> rep region
    gemm256<<<gblk, 256, 0, stream>>>(features, W1, bufA, N);
    spmm_gather<<<wblk, 256, 0, stream>>>(rowptr, colIdx, bufA, dinv, b1, rep, N, 1);

    // conv2: h2 = x1 @ W2 (bufA); x2 = gather + selfloop + b2 -> rep (overwrites x1)
    gemm256<<<gblk, 256, 0, stream>>>(rep, W2, bufA, N);
    spmm_gather<<<wblk, 256, 0, stream>>>(rowptr, colIdx, bufA, dinv, b2, rep, N, 0);

    // rep = l2norm(l2norm(x2)) in place
    l2norm2<<<wblk, 256, 0, stream>>>(rep, N);

    // y = rep @ Wy + by
    gemm_wy<<<gblk, 256, 0, stream>>>(rep, Wy, by, y, N);

    // loss
    hipMemsetAsync(accum, 0, 16, stream);
    loss_kernel<<<2048, 256, 0, stream>>>(e0, e1, n0, n1, rep, features, ls, accum, E);
    loss_final<<<1, 1, 0, stream>>>(accum, rec, N);
}

// Round 3
// 1137.959 us; speedup vs baseline: 5.6111x; 1.2460x over previous
//
#include <hip/hip_runtime.h>
#include <hip/hip_bf16.h>

#define FEAT 256
#define HDIM 256
#define CDIM 64
#define THETA 0.5f

// ---------------- degree ----------------
__global__ __launch_bounds__(256) void deg_count(const int* __restrict__ e0, int E, int* deg) {
    int i = blockIdx.x * 256 + threadIdx.x;
    if (i < E) atomicAdd(&deg[e0[i]], 1);
}

__global__ __launch_bounds__(256) void make_dinv(const int* __restrict__ deg, float* __restrict__ dinv, int N) {
    int i = blockIdx.x * 256 + threadIdx.x;
    if (i < N) dinv[i] = rsqrtf((float)(deg[i] + 1));  // +1 self loop
}

// ---------------- single-block exclusive scan -> rowptr, cursor ----------------
__global__ __launch_bounds__(256) void scan_rowptr(const int* __restrict__ deg,
                                                   int* __restrict__ rowptr,
                                                   int* __restrict__ cursor, int N) {
    __shared__ int part[256];
    const int tid = threadIdx.x;
    const int chunk = (N + 255) / 256;
    const int s = tid * chunk;
    const int e = min(s + chunk, N);
    int sum = 0;
    for (int i = s; i < e; ++i) sum += deg[i];
    part[tid] = sum;
    __syncthreads();
#pragma unroll
    for (int off = 1; off < 256; off <<= 1) {
        int t = (tid >= off) ? part[tid - off] : 0;
        __syncthreads();
        part[tid] += t;
        __syncthreads();
    }
    int run = part[tid] - sum;  // exclusive prefix
    for (int i = s; i < e; ++i) {
        rowptr[i] = run;
        cursor[i] = run;
        run += deg[i];
    }
    if (tid == 255) rowptr[N] = run;
}

// ---------------- bucket edges into CSR ----------------
__global__ __launch_bounds__(256) void bucket_edges(const int* __restrict__ e0,
                                                    const int* __restrict__ e1,
                                                    int* cursor, int* __restrict__ colIdx, int E) {
    int i = blockIdx.x * 256 + threadIdx.x;
    if (i < E) {
        int r = e0[i];
        int pos = atomicAdd(&cursor[r], 1);
        colIdx[pos] = e1[i];
    }
}

// ---------------- fp32 -> bf16 table conversion (RNE) ----------------
__device__ __forceinline__ unsigned short f2bf(float f) {
    unsigned int u = __float_as_uint(f);
    u += 0x7fffu + ((u >> 16) & 1u);
    return (unsigned short)(u >> 16);
}

__global__ __launch_bounds__(256) void to_bf16(const float* __restrict__ src,
                                               unsigned short* __restrict__ dst, int n8) {
    int i = blockIdx.x * 256 + threadIdx.x;  // one thread per 8 floats
    if (i >= n8) return;
    float4 a = ((const float4*)src)[2 * i];
    float4 b = ((const float4*)src)[2 * i + 1];
    uint4 o;
    o.x = (unsigned int)f2bf(a.x) | ((unsigned int)f2bf(a.y) << 16);
    o.y = (unsigned int)f2bf(a.z) | ((unsigned int)f2bf(a.w) << 16);
    o.z = (unsigned int)f2bf(b.x) | ((unsigned int)f2bf(b.y) << 16);
    o.w = (unsigned int)f2bf(b.z) | ((unsigned int)f2bf(b.w) << 16);
    ((uint4*)dst)[i] = o;
}

// ---------------- fp32 GEMM: out[M,256] = A[M,256] @ W[256,256] ----------------
__global__ __launch_bounds__(256) void gemm256(const float* __restrict__ A,
                                               const float* __restrict__ W,
                                               float* __restrict__ out, int M) {
    __shared__ float Wl[32][256];
    __shared__ float Al[64][40];
    const int tid = threadIdx.x;
    const int m0 = blockIdx.x * 64;
    const int c0 = (tid & 63) * 4;
    const int r0 = (tid >> 6) * 16;
    float4 acc[16];
#pragma unroll
    for (int i = 0; i < 16; ++i) acc[i] = make_float4(0.f, 0.f, 0.f, 0.f);

    for (int k0 = 0; k0 < 256; k0 += 32) {
#pragma unroll
        for (int i = 0; i < 8; ++i) {
            int j = i * 256 + tid;
            int kk = j >> 6;
            int c4 = (j & 63) * 4;
            float4 v = *(const float4*)&W[(size_t)(k0 + kk) * 256 + c4];
            *(float4*)&Wl[kk][c4] = v;
        }
#pragma unroll
        for (int i = 0; i < 2; ++i) {
            int j = i * 256 + tid;
            int r = j >> 3;
            int k4 = (j & 7) * 4;
            int row = m0 + r;
            float4 v = (row < M) ? *(const float4*)&A[(size_t)row * 256 + k0 + k4]
                                 : make_float4(0.f, 0.f, 0.f, 0.f);
            *(float4*)&Al[r][k4] = v;
        }
        __syncthreads();
#pragma unroll
        for (int kk = 0; kk < 32; kk += 4) {
            float4 w0 = *(float4*)&Wl[kk + 0][c0];
            float4 w1 = *(float4*)&Wl[kk + 1][c0];
            float4 w2 = *(float4*)&Wl[kk + 2][c0];
            float4 w3 = *(float4*)&Wl[kk + 3][c0];
#pragma unroll
            for (int i = 0; i < 16; ++i) {
                float4 a = *(float4*)&Al[r0 + i][kk];
                acc[i].x = fmaf(a.x, w0.x, acc[i].x);
                acc[i].y = fmaf(a.x, w0.y, acc[i].y);
                acc[i].z = fmaf(a.x, w0.z, acc[i].z);
                acc[i].w = fmaf(a.x, w0.w, acc[i].w);
                acc[i].x = fmaf(a.y, w1.x, acc[i].x);
                acc[i].y = fmaf(a.y, w1.y, acc[i].y);
                acc[i].z = fmaf(a.y, w1.z, acc[i].z);
                acc[i].w = fmaf(a.y, w1.w, acc[i].w);
                acc[i].x = fmaf(a.z, w2.x, acc[i].x);
                acc[i].y = fmaf(a.z, w2.y, acc[i].y);
                acc[i].z = fmaf(a.z, w2.z, acc[i].z);
                acc[i].w = fmaf(a.z, w2.w, acc[i].w);
                acc[i].x = fmaf(a.w, w3.x, acc[i].x);
                acc[i].y = fmaf(a.w, w3.y, acc[i].y);
                acc[i].z = fmaf(a.w, w3.z, acc[i].z);
                acc[i].w = fmaf(a.w, w3.w, acc[i].w);
            }
        }
        __syncthreads();
    }
#pragma unroll
    for (int i = 0; i < 16; ++i) {
        int row = m0 + r0 + i;
        if (row < M) *(float4*)&out[(size_t)row * 256 + c0] = acc[i];
    }
}

// ---------------- CSR gather SpMM fused with finalize ----------------
__global__ __launch_bounds__(256) void spmm_gather(const int* __restrict__ rowptr,
                                                   const int* __restrict__ colIdx,
                                                   const float* __restrict__ h,
                                                   const float* __restrict__ dinv,
                                                   const float* __restrict__ bias,
                                                   float* __restrict__ out,
                                                   int N, int do_relu) {
    int row = (blockIdx.x * 256 + threadIdx.x) >> 6;
    int lane = threadIdx.x & 63;
    if (row >= N) return;
    int beg = rowptr[row];
    int end = rowptr[row + 1];
    float4 acc = make_float4(0.f, 0.f, 0.f, 0.f);
    int j = beg;
    for (; j + 3 < end; j += 4) {
        int c0 = colIdx[j + 0];
        int c1 = colIdx[j + 1];
        int c2 = colIdx[j + 2];
        int c3 = colIdx[j + 3];
        float w0 = dinv[c0], w1 = dinv[c1], w2 = dinv[c2], w3 = dinv[c3];
        float4 h0 = *(const float4*)&h[(size_t)c0 * 256 + lane * 4];
        float4 h1 = *(const float4*)&h[(size_t)c1 * 256 + lane * 4];
        float4 h2 = *(const float4*)&h[(size_t)c2 * 256 + lane * 4];
        float4 h3 = *(const float4*)&h[(size_t)c3 * 256 + lane * 4];
        acc.x = fmaf(w0, h0.x, acc.x); acc.y = fmaf(w0, h0.y, acc.y);
        acc.z = fmaf(w0, h0.z, acc.z); acc.w = fmaf(w0, h0.w, acc.w);
        acc.x = fmaf(w1, h1.x, acc.x); acc.y = fmaf(w1, h1.y, acc.y);
        acc.z = fmaf(w1, h1.z, acc.z); acc.w = fmaf(w1, h1.w, acc.w);
        acc.x = fmaf(w2, h2.x, acc.x); acc.y = fmaf(w2, h2.y, acc.y);
        acc.z = fmaf(w2, h2.z, acc.z); acc.w = fmaf(w2, h2.w, acc.w);
        acc.x = fmaf(w3, h3.x, acc.x); acc.y = fmaf(w3, h3.y, acc.y);
        acc.z = fmaf(w3, h3.z, acc.z); acc.w = fmaf(w3, h3.w, acc.w);
    }
    for (; j < end; ++j) {
        int c = colIdx[j];
        float w = dinv[c];
        float4 hv = *(const float4*)&h[(size_t)c * 256 + lane * 4];
        acc.x = fmaf(w, hv.x, acc.x); acc.y = fmaf(w, hv.y, acc.y);
        acc.z = fmaf(w, hv.z, acc.z); acc.w = fmaf(w, hv.w, acc.w);
    }
    float di = dinv[row];
    float s = di * di;
    float4 hv = *(const float4*)&h[(size_t)row * 256 + lane * 4];
    float4 bv = *(const float4*)&bias[lane * 4];
    float4 r;
    r.x = fmaf(di, acc.x, fmaf(s, hv.x, bv.x));
    r.y = fmaf(di, acc.y, fmaf(s, hv.y, bv.y));
    r.z = fmaf(di, acc.z, fmaf(s, hv.z, bv.z));
    r.w = fmaf(di, acc.w, fmaf(s, hv.w, bv.w));
    if (do_relu) {
        r.x = fmaxf(r.x, 0.f);
        r.y = fmaxf(r.y, 0.f);
        r.z = fmaxf(r.z, 0.f);
        r.w = fmaxf(r.w, 0.f);
    }
    *(float4*)&out[(size_t)row * 256 + lane * 4] = r;
}

// ---------------- double L2 normalize, in place, one wave per row ----------------
__global__ __launch_bounds__(256) void l2norm2(float* __restrict__ rep, int N) {
    int gw = (blockIdx.x * 256 + threadIdx.x) >> 6;
    int lane = threadIdx.x & 63;
    if (gw >= N) return;
    float4 v = *(float4*)&rep[(size_t)gw * 256 + lane * 4];
    float ss = v.x * v.x + v.y * v.y + v.z * v.z + v.w * v.w;
#pragma unroll
    for (int o = 1; o < 64; o <<= 1) ss += __shfl_xor(ss, o);
    float inv = 1.0f / fmaxf(sqrtf(ss), 1e-12f);
    v.x *= inv; v.y *= inv; v.z *= inv; v.w *= inv;
    float ss2 = v.x * v.x + v.y * v.y + v.z * v.z + v.w * v.w;
#pragma unroll
    for (int o = 1; o < 64; o <<= 1) ss2 += __shfl_xor(ss2, o);
    float inv2 = 1.0f / fmaxf(sqrtf(ss2), 1e-12f);
    v.x *= inv2; v.y *= inv2; v.z *= inv2; v.w *= inv2;
    *(float4*)&rep[(size_t)gw * 256 + lane * 4] = v;
}

// ---------------- head GEMM: y[M,64] = rep[M,256] @ Wy[256,64] + by ----------------
__global__ __launch_bounds__(256) void gemm_wy(const float* __restrict__ A,
                                               const float* __restrict__ W,
                                               const float* __restrict__ bias,
                                               float* __restrict__ out, int M) {
    __shared__ float Wl[32][64];
    __shared__ float Al[64][40];
    const int tid = threadIdx.x;
    const int m0 = blockIdx.x * 64;
    const int c0 = (tid & 15) * 4;
    const int r0 = (tid >> 4) * 4;
    float4 acc[4];
#pragma unroll
    for (int i = 0; i < 4; ++i) acc[i] = make_float4(0.f, 0.f, 0.f, 0.f);

    for (int k0 = 0; k0 < 256; k0 += 32) {
#pragma unroll
        for (int i = 0; i < 2; ++i) {
            int j = i * 256 + tid;
            int kk = j >> 4;
            int c4 = (j & 15) * 4;
            float4 v = *(const float4*)&W[(size_t)(k0 + kk) * 64 + c4];
            *(float4*)&Wl[kk][c4] = v;
        }
#pragma unroll
        for (int i = 0; i < 2; ++i) {
            int j = i * 256 + tid;
            int r = j >> 3;
            int k4 = (j & 7) * 4;
            int row = m0 + r;
            float4 v = (row < M) ? *(const float4*)&A[(size_t)row * 256 + k0 + k4]
                                 : make_float4(0.f, 0.f, 0.f, 0.f);
            *(float4*)&Al[r][k4] = v;
        }
        __syncthreads();
#pragma unroll
        for (int kk = 0; kk < 32; kk += 4) {
            float4 w0 = *(float4*)&Wl[kk + 0][c0];
            float4 w1 = *(float4*)&Wl[kk + 1][c0];
            float4 w2 = *(float4*)&Wl[kk + 2][c0];
            float4 w3 = *(float4*)&Wl[kk + 3][c0];
#pragma unroll
            for (int i = 0; i < 4; ++i) {
                float4 a = *(float4*)&Al[r0 + i][kk];
                acc[i].x = fmaf(a.x, w0.x, acc[i].x);
                acc[i].y = fmaf(a.x, w0.y, acc[i].y);
                acc[i].z = fmaf(a.x, w0.z, acc[i].z);
                acc[i].w = fmaf(a.x, w0.w, acc[i].w);
                acc[i].x = fmaf(a.y, w1.x, acc[i].x);
                acc[i].y = fmaf(a.y, w1.y, acc[i].y);
                acc[i].z = fmaf(a.y, w1.z, acc[i].z);
                acc[i].w = fmaf(a.y, w1.w, acc[i].w);
                acc[i].x = fmaf(a.z, w2.x, acc[i].x);
                acc[i].y = fmaf(a.z, w2.y, acc[i].y);
                acc[i].z = fmaf(a.z, w2.z, acc[i].z);
                acc[i].w = fmaf(a.z, w2.w, acc[i].w);
                acc[i].x = fmaf(a.w, w3.x, acc[i].x);
                acc[i].y = fmaf(a.w, w3.y, acc[i].y);
                acc[i].z = fmaf(a.w, w3.z, acc[i].z);
                acc[i].w = fmaf(a.w, w3.w, acc[i].w);
            }
        }
        __syncthreads();
    }
    float4 bv = *(const float4*)&bias[c0];
#pragma unroll
    for (int i = 0; i < 4; ++i) {
        int row = m0 + r0 + i;
        if (row < M) {
            float* o = &out[(size_t)row * 64 + c0];
            o[0] = acc[i].x + bv.x;
            o[1] = acc[i].y + bv.y;
            o[2] = acc[i].z + bv.z;
            o[3] = acc[i].w + bv.w;
        }
    }
}

// ---------------- reconstruction loss (bf16 gather tables, fp32 accumulate) ----------------
__device__ __forceinline__ float bfl(unsigned int u) { return __uint_as_float(u << 16); }
__device__ __forceinline__ float bfh(unsigned int u) { return __uint_as_float(u & 0xffff0000u); }

__global__ __launch_bounds__(256) void loss_kernel(const int* __restrict__ e0,
                                                   const int* __restrict__ e1,
                                                   const int* __restrict__ n0,
                                                   const int* __restrict__ n1,
                                                   const unsigned short* __restrict__ repB,
                                                   const unsigned short* __restrict__ featB,
                                                   const float* __restrict__ ls,
                                                   float* accum, int E) {
    const int lane = threadIdx.x & 63;
    const int wline = threadIdx.x >> 6;
    const int gw = blockIdx.x * 4 + wline;
    const int nw = gridDim.x * 4;
    float ap = 0.f, an = 0.f, cp = 0.f, cn = 0.f;
    for (int e = gw; e < E; e += nw) {
        int a = e0[e], b = e1[e];
        int c = n0[e], d = n1[e];
        const uint2 ra = *(const uint2*)&repB[(size_t)a * 256 + lane * 4];
        const uint2 rb = *(const uint2*)&repB[(size_t)b * 256 + lane * 4];
        const uint2 fa = *(const uint2*)&featB[(size_t)a * 256 + lane * 4];
        const uint2 fb = *(const uint2*)&featB[(size_t)b * 256 + lane * 4];
        const uint2 rc = *(const uint2*)&repB[(size_t)c * 256 + lane * 4];
        const uint2 rd = *(const uint2*)&repB[(size_t)d * 256 + lane * 4];
        float dp = bfl(ra.x) * bfl(rb.x) + bfh(ra.x) * bfh(rb.x)
                 + bfl(ra.y) * bfl(rb.y) + bfh(ra.y) * bfh(rb.y);
        float df = bfl(fa.x) * bfl(fb.x) + bfh(fa.x) * bfh(fb.x)
                 + bfl(fa.y) * bfl(fb.y) + bfh(fa.y) * bfh(fb.y);
        float dn = bfl(rc.x) * bfl(rd.x) + bfh(rc.x) * bfh(rd.x)
                 + bfl(rc.y) * bfl(rd.y) + bfh(rc.y) * bfh(rd.y);
#pragma unroll
        for (int o = 1; o < 64; o <<= 1) {
            dp += __shfl_xor(dp, o);
            df += __shfl_xor(df, o);
            dn += __shfl_xor(dn, o);
        }
        if (lane == 0) {
            if (a < b) {
                float pw = fmaxf(dp, 0.f);
                float pos = THETA * df + (1.0f - THETA) * pw;
                float t = pos - ls[e];
                ap += t * t;
                cp += 1.f;
            }
            if (c < d) {
                float nwt = fmaxf(dn, 0.f);
                an += nwt * nwt;
                cn += 1.f;
            }
        }
    }
    __shared__ float s[4][4];
    if (lane == 0) {
        s[wline][0] = ap;
        s[wline][1] = an;
        s[wline][2] = cp;
        s[wline][3] = cn;
    }
    __syncthreads();
    if (threadIdx.x == 0) {
        float tp = 0.f, tn = 0.f, tcp = 0.f, tcn = 0.f;
#pragma unroll
        for (int w = 0; w < 4; ++w) {
            tp += s[w][0];
            tn += s[w][1];
            tcp += s[w][2];
            tcn += s[w][3];
        }
        unsafeAtomicAdd(&accum[0], tp);
        unsafeAtomicAdd(&accum[1], tn);
        unsafeAtomicAdd(&accum[2], tcp);
        unsafeAtomicAdd(&accum[3], tcn);
    }
}

__global__ void loss_final(const float* __restrict__ accum, float* __restrict__ out, int N) {
    out[0] = (accum[1] + accum[0]) * (float)N / (accum[3] + accum[2]);
}

// ---------------- launcher ----------------
extern "C" void kernel_launch(void* const* d_in, const int* in_sizes, int n_in,
                              void* d_out, int out_size, void* d_ws, size_t ws_size,
                              hipStream_t stream) {
    const int* edge = (const int*)d_in[0];
    const float* features = (const float*)d_in[1];
    const float* ls = (const float*)d_in[2];
    const int* nedge = (const int*)d_in[3];
    const float* W1 = (const float*)d_in[4];
    const float* b1 = (const float*)d_in[5];
    const float* W2 = (const float*)d_in[6];
    const float* b2 = (const float*)d_in[7];
    const float* Wy = (const float*)d_in[8];
    const float* by = (const float*)d_in[9];

    const int E = in_sizes[0] / 2;
    const int N = in_sizes[1] / FEAT;
    const int* e0 = edge;
    const int* e1 = edge + E;
    const int* n0 = nedge;
    const int* n1 = nedge + E;

    float* rep = (float*)d_out;          // [N,256] — also used as x1/x2 staging
    float* rec = rep + (size_t)N * 256;  // scalar
    float* y = rec + 1;                  // [N,64], 4B-aligned only

    // workspace carve-out
    char* base = (char*)d_ws;
    size_t off = 0;
    auto carve = [&](size_t bytes) -> void* {
        void* p = base + off;
        off += (bytes + 1023) & ~(size_t)1023;
        return p;
    };
    int* deg = (int*)carve((size_t)N * 4);
    float* dinv = (float*)carve((size_t)N * 4);
    float* accum = (float*)carve(16);
    int* rowptr = (int*)carve((size_t)(N + 1) * 4);
    int* cursor = (int*)carve((size_t)N * 4);
    int* colIdx = (int*)carve((size_t)E * 4);
    float* bufA = (float*)carve((size_t)N * 256 * 4);
    unsigned short* featB = (unsigned short*)carve((size_t)N * 256 * 2);
    unsigned short* repB = (unsigned short*)carve((size_t)N * 256 * 2);

    // CSR build
    hipMemsetAsync(deg, 0, (size_t)N * 4, stream);
    deg_count<<<(E + 255) / 256, 256, 0, stream>>>(e0, E, deg);
    make_dinv<<<(N + 255) / 256, 256, 0, stream>>>(deg, dinv, N);
    scan_rowptr<<<1, 256, 0, stream>>>(deg, rowptr, cursor, N);
    bucket_edges<<<(E + 255) / 256, 256, 0, stream>>>(e0, e1, cursor, colIdx, E);

    const int gblk = (N + 63) / 64;
    const int wblk = (N + 3) / 4;
    const int n8 = N * 256 / 8;

    // bf16 feature table for the loss
    to_bf16<<<(n8 + 255) / 256, 256, 0, stream>>>(features, featB, n8);

    // conv1: h1 = features @ W1 (bufA); x1 = relu(gather + selfloop + b1) -> rep region
    gemm256<<<gblk, 256, 0, stream>>>(features, W1, bufA, N);
    spmm_gather<<<wblk, 256, 0, stream>>>(rowptr, colIdx, bufA, dinv, b1, rep, N, 1);

    // conv2: h2 = x1 @ W2 (bufA); x2 = gather + selfloop + b2 -> rep (overwrites x1)
    gemm256<<<gblk, 256, 0, stream>>>(rep, W2, bufA, N);
    spmm_gather<<<wblk, 256, 0, stream>>>(rowptr, colIdx, bufA, dinv, b2, rep, N, 0);

    // rep = l2norm(l2norm(x2)) in place
    l2norm2<<<wblk, 256, 0, stream>>>(rep, N);

    // bf16 rep table for the loss
    to_bf16<<<(n8 + 255) / 256, 256, 0, stream>>>(rep, repB, n8);

    // y = rep @ Wy + by
    gemm_wy<<<gblk, 256, 0, stream>>>(rep, Wy, by, y, N);

    // loss
    hipMemsetAsync(accum, 0, 16, stream);
    loss_kernel<<<2048, 256, 0, stream>>>(e0, e1, n0, n1, repB, featB, ls, accum, E);
    loss_final<<<1, 1, 0, stream>>>(accum, rec, N);
}

// Round 4
// 849.938 us; speedup vs baseline: 7.5125x; 1.3389x over previous
//
#include <hip/hip_runtime.h>
#include <hip/hip_bf16.h>

#define FEAT 256
#define HDIM 256
#define CDIM 64
#define THETA 0.5f

typedef float floatx2 __attribute__((ext_vector_type(2)));

// ---------------- degree ----------------
__global__ __launch_bounds__(256) void deg_count(const int* __restrict__ e0, int E, int* deg) {
    int i = blockIdx.x * 256 + threadIdx.x;
    if (i < E) atomicAdd(&deg[e0[i]], 1);
}

__global__ __launch_bounds__(256) void make_dinv(const int* __restrict__ deg, float* __restrict__ dinv, int N) {
    int i = blockIdx.x * 256 + threadIdx.x;
    if (i < N) dinv[i] = rsqrtf((float)(deg[i] + 1));  // +1 self loop
}

// ---------------- single-block exclusive scan -> rowptr, cursor ----------------
__global__ __launch_bounds__(256) void scan_rowptr(const int* __restrict__ deg,
                                                   int* __restrict__ rowptr,
                                                   int* __restrict__ cursor, int N) {
    __shared__ int part[256];
    const int tid = threadIdx.x;
    const int chunk = (N + 255) / 256;
    const int s = tid * chunk;
    const int e = min(s + chunk, N);
    int sum = 0;
    for (int i = s; i < e; ++i) sum += deg[i];
    part[tid] = sum;
    __syncthreads();
#pragma unroll
    for (int off = 1; off < 256; off <<= 1) {
        int t = (tid >= off) ? part[tid - off] : 0;
        __syncthreads();
        part[tid] += t;
        __syncthreads();
    }
    int run = part[tid] - sum;  // exclusive prefix
    for (int i = s; i < e; ++i) {
        rowptr[i] = run;
        cursor[i] = run;
        run += deg[i];
    }
    if (tid == 255) rowptr[N] = run;
}

// ---------------- bucket edges into CSR ----------------
__global__ __launch_bounds__(256) void bucket_edges(const int* __restrict__ e0,
                                                    const int* __restrict__ e1,
                                                    int* cursor, int* __restrict__ colIdx, int E) {
    int i = blockIdx.x * 256 + threadIdx.x;
    if (i < E) {
        int r = e0[i];
        int pos = atomicAdd(&cursor[r], 1);
        colIdx[pos] = e1[i];
    }
}

// ---------------- conversions ----------------
__device__ __forceinline__ unsigned short f2bf(float f) {
    unsigned int u = __float_as_uint(f);
    u += 0x7fffu + ((u >> 16) & 1u);
    return (unsigned short)(u >> 16);
}
__device__ __forceinline__ float bfl(unsigned int u) { return __uint_as_float(u << 16); }
__device__ __forceinline__ float bfh(unsigned int u) { return __uint_as_float(u & 0xffff0000u); }

__global__ __launch_bounds__(256) void to_bf16(const float* __restrict__ src,
                                               unsigned short* __restrict__ dst, int n8) {
    int i = blockIdx.x * 256 + threadIdx.x;  // one thread per 8 floats
    if (i >= n8) return;
    float4 a = ((const float4*)src)[2 * i];
    float4 b = ((const float4*)src)[2 * i + 1];
    uint4 o;
    o.x = (unsigned int)f2bf(a.x) | ((unsigned int)f2bf(a.y) << 16);
    o.y = (unsigned int)f2bf(a.z) | ((unsigned int)f2bf(a.w) << 16);
    o.z = (unsigned int)f2bf(b.x) | ((unsigned int)f2bf(b.y) << 16);
    o.w = (unsigned int)f2bf(b.z) | ((unsigned int)f2bf(b.w) << 16);
    ((uint4*)dst)[i] = o;
}

__global__ __launch_bounds__(256) void to_fp8(const float* __restrict__ src,
                                              unsigned char* __restrict__ dst, int n8) {
    int i = blockIdx.x * 256 + threadIdx.x;  // one thread per 8 floats
    if (i >= n8) return;
    float4 a = ((const float4*)src)[2 * i];
    float4 b = ((const float4*)src)[2 * i + 1];
    int w0 = __builtin_amdgcn_cvt_pk_fp8_f32(a.x, a.y, 0, false);
    w0 = __builtin_amdgcn_cvt_pk_fp8_f32(a.z, a.w, w0, true);
    int w1 = __builtin_amdgcn_cvt_pk_fp8_f32(b.x, b.y, 0, false);
    w1 = __builtin_amdgcn_cvt_pk_fp8_f32(b.z, b.w, w1, true);
    uint2 o;
    o.x = (unsigned int)w0;
    o.y = (unsigned int)w1;
    ((uint2*)dst)[i] = o;
}

// ---------------- fp32 GEMM with bf16 output: out[M,256] = bf16(A[M,256] @ W[256,256]) ----------------
__global__ __launch_bounds__(256) void gemm256_obf16(const float* __restrict__ A,
                                                     const float* __restrict__ W,
                                                     unsigned short* __restrict__ out, int M) {
    __shared__ float Wl[32][256];
    __shared__ float Al[64][40];
    const int tid = threadIdx.x;
    const int m0 = blockIdx.x * 64;
    const int c0 = (tid & 63) * 4;
    const int r0 = (tid >> 6) * 16;
    float4 acc[16];
#pragma unroll
    for (int i = 0; i < 16; ++i) acc[i] = make_float4(0.f, 0.f, 0.f, 0.f);

    for (int k0 = 0; k0 < 256; k0 += 32) {
#pragma unroll
        for (int i = 0; i < 8; ++i) {
            int j = i * 256 + tid;
            int kk = j >> 6;
            int c4 = (j & 63) * 4;
            float4 v = *(const float4*)&W[(size_t)(k0 + kk) * 256 + c4];
            *(float4*)&Wl[kk][c4] = v;
        }
#pragma unroll
        for (int i = 0; i < 2; ++i) {
            int j = i * 256 + tid;
            int r = j >> 3;
            int k4 = (j & 7) * 4;
            int row = m0 + r;
            float4 v = (row < M) ? *(const float4*)&A[(size_t)row * 256 + k0 + k4]
                                 : make_float4(0.f, 0.f, 0.f, 0.f);
            *(float4*)&Al[r][k4] = v;
        }
        __syncthreads();
#pragma unroll
        for (int kk = 0; kk < 32; kk += 4) {
            float4 w0 = *(float4*)&Wl[kk + 0][c0];
            float4 w1 = *(float4*)&Wl[kk + 1][c0];
            float4 w2 = *(float4*)&Wl[kk + 2][c0];
            float4 w3 = *(float4*)&Wl[kk + 3][c0];
#pragma unroll
            for (int i = 0; i < 16; ++i) {
                float4 a = *(float4*)&Al[r0 + i][kk];
                acc[i].x = fmaf(a.x, w0.x, acc[i].x);
                acc[i].y = fmaf(a.x, w0.y, acc[i].y);
                acc[i].z = fmaf(a.x, w0.z, acc[i].z);
                acc[i].w = fmaf(a.x, w0.w, acc[i].w);
                acc[i].x = fmaf(a.y, w1.x, acc[i].x);
                acc[i].y = fmaf(a.y, w1.y, acc[i].y);
                acc[i].z = fmaf(a.y, w1.z, acc[i].z);
                acc[i].w = fmaf(a.y, w1.w, acc[i].w);
                acc[i].x = fmaf(a.z, w2.x, acc[i].x);
                acc[i].y = fmaf(a.z, w2.y, acc[i].y);
                acc[i].z = fmaf(a.z, w2.z, acc[i].z);
                acc[i].w = fmaf(a.z, w2.w, acc[i].w);
                acc[i].x = fmaf(a.w, w3.x, acc[i].x);
                acc[i].y = fmaf(a.w, w3.y, acc[i].y);
                acc[i].z = fmaf(a.w, w3.z, acc[i].z);
                acc[i].w = fmaf(a.w, w3.w, acc[i].w);
            }
        }
        __syncthreads();
    }
#pragma unroll
    for (int i = 0; i < 16; ++i) {
        int row = m0 + r0 + i;
        if (row < M) {
            uint2 o;
            o.x = (unsigned int)f2bf(acc[i].x) | ((unsigned int)f2bf(acc[i].y) << 16);
            o.y = (unsigned int)f2bf(acc[i].z) | ((unsigned int)f2bf(acc[i].w) << 16);
            *(uint2*)&out[(size_t)row * 256 + c0] = o;
        }
    }
}

// ---------------- CSR gather SpMM (bf16 h table) fused with finalize ----------------
__global__ __launch_bounds__(256) void spmm_gather_b16(const int* __restrict__ rowptr,
                                                       const int* __restrict__ colIdx,
                                                       const unsigned short* __restrict__ h,
                                                       const float* __restrict__ dinv,
                                                       const float* __restrict__ bias,
                                                       float* __restrict__ out,
                                                       int N, int do_relu) {
    int row = (blockIdx.x * 256 + threadIdx.x) >> 6;
    int lane = threadIdx.x & 63;
    if (row >= N) return;
    int beg = rowptr[row];
    int end = rowptr[row + 1];
    float4 acc = make_float4(0.f, 0.f, 0.f, 0.f);
    int j = beg;
    for (; j + 3 < end; j += 4) {
        int c0 = colIdx[j + 0];
        int c1 = colIdx[j + 1];
        int c2 = colIdx[j + 2];
        int c3 = colIdx[j + 3];
        float w0 = dinv[c0], w1 = dinv[c1], w2 = dinv[c2], w3 = dinv[c3];
        uint2 h0 = *(const uint2*)&h[(size_t)c0 * 256 + lane * 4];
        uint2 h1 = *(const uint2*)&h[(size_t)c1 * 256 + lane * 4];
        uint2 h2 = *(const uint2*)&h[(size_t)c2 * 256 + lane * 4];
        uint2 h3 = *(const uint2*)&h[(size_t)c3 * 256 + lane * 4];
        acc.x = fmaf(w0, bfl(h0.x), acc.x); acc.y = fmaf(w0, bfh(h0.x), acc.y);
        acc.z = fmaf(w0, bfl(h0.y), acc.z); acc.w = fmaf(w0, bfh(h0.y), acc.w);
        acc.x = fmaf(w1, bfl(h1.x), acc.x); acc.y = fmaf(w1, bfh(h1.x), acc.y);
        acc.z = fmaf(w1, bfl(h1.y), acc.z); acc.w = fmaf(w1, bfh(h1.y), acc.w);
        acc.x = fmaf(w2, bfl(h2.x), acc.x); acc.y = fmaf(w2, bfh(h2.x), acc.y);
        acc.z = fmaf(w2, bfl(h2.y), acc.z); acc.w = fmaf(w2, bfh(h2.y), acc.w);
        acc.x = fmaf(w3, bfl(h3.x), acc.x); acc.y = fmaf(w3, bfh(h3.x), acc.y);
        acc.z = fmaf(w3, bfl(h3.y), acc.z); acc.w = fmaf(w3, bfh(h3.y), acc.w);
    }
    for (; j < end; ++j) {
        int c = colIdx[j];
        float w = dinv[c];
        uint2 hv = *(const uint2*)&h[(size_t)c * 256 + lane * 4];
        acc.x = fmaf(w, bfl(hv.x), acc.x); acc.y = fmaf(w, bfh(hv.x), acc.y);
        acc.z = fmaf(w, bfl(hv.y), acc.z); acc.w = fmaf(w, bfh(hv.y), acc.w);
    }
    float di = dinv[row];
    float s = di * di;
    uint2 hv = *(const uint2*)&h[(size_t)row * 256 + lane * 4];
    float4 bv = *(const float4*)&bias[lane * 4];
    float4 r;
    r.x = fmaf(di, acc.x, fmaf(s, bfl(hv.x), bv.x));
    r.y = fmaf(di, acc.y, fmaf(s, bfh(hv.x), bv.y));
    r.z = fmaf(di, acc.z, fmaf(s, bfl(hv.y), bv.z));
    r.w = fmaf(di, acc.w, fmaf(s, bfh(hv.y), bv.w));
    if (do_relu) {
        r.x = fmaxf(r.x, 0.f);
        r.y = fmaxf(r.y, 0.f);
        r.z = fmaxf(r.z, 0.f);
        r.w = fmaxf(r.w, 0.f);
    }
    *(float4*)&out[(size_t)row * 256 + lane * 4] = r;
}

// ---------------- double L2 normalize, in place, one wave per row ----------------
__global__ __launch_bounds__(256) void l2norm2(float* __restrict__ rep, int N) {
    int gw = (blockIdx.x * 256 + threadIdx.x) >> 6;
    int lane = threadIdx.x & 63;
    if (gw >= N) return;
    float4 v = *(float4*)&rep[(size_t)gw * 256 + lane * 4];
    float ss = v.x * v.x + v.y * v.y + v.z * v.z + v.w * v.w;
#pragma unroll
    for (int o = 1; o < 64; o <<= 1) ss += __shfl_xor(ss, o);
    float inv = 1.0f / fmaxf(sqrtf(ss), 1e-12f);
    v.x *= inv; v.y *= inv; v.z *= inv; v.w *= inv;
    float ss2 = v.x * v.x + v.y * v.y + v.z * v.z + v.w * v.w;
#pragma unroll
    for (int o = 1; o < 64; o <<= 1) ss2 += __shfl_xor(ss2, o);
    float inv2 = 1.0f / fmaxf(sqrtf(ss2), 1e-12f);
    v.x *= inv2; v.y *= inv2; v.z *= inv2; v.w *= inv2;
    *(float4*)&rep[(size_t)gw * 256 + lane * 4] = v;
}

// ---------------- head GEMM: y[M,64] = rep[M,256] @ Wy[256,64] + by ----------------
__global__ __launch_bounds__(256) void gemm_wy(const float* __restrict__ A,
                                               const float* __restrict__ W,
                                               const float* __restrict__ bias,
                                               float* __restrict__ out, int M) {
    __shared__ float Wl[32][64];
    __shared__ float Al[64][40];
    const int tid = threadIdx.x;
    const int m0 = blockIdx.x * 64;
    const int c0 = (tid & 15) * 4;
    const int r0 = (tid >> 4) * 4;
    float4 acc[4];
#pragma unroll
    for (int i = 0; i < 4; ++i) acc[i] = make_float4(0.f, 0.f, 0.f, 0.f);

    for (int k0 = 0; k0 < 256; k0 += 32) {
#pragma unroll
        for (int i = 0; i < 2; ++i) {
            int j = i * 256 + tid;
            int kk = j >> 4;
            int c4 = (j & 15) * 4;
            float4 v = *(const float4*)&W[(size_t)(k0 + kk) * 64 + c4];
            *(float4*)&Wl[kk][c4] = v;
        }
#pragma unroll
        for (int i = 0; i < 2; ++i) {
            int j = i * 256 + tid;
            int r = j >> 3;
            int k4 = (j & 7) * 4;
            int row = m0 + r;
            float4 v = (row < M) ? *(const float4*)&A[(size_t)row * 256 + k0 + k4]
                                 : make_float4(0.f, 0.f, 0.f, 0.f);
            *(float4*)&Al[r][k4] = v;
        }
        __syncthreads();
#pragma unroll
        for (int kk = 0; kk < 32; kk += 4) {
            float4 w0 = *(float4*)&Wl[kk + 0][c0];
            float4 w1 = *(float4*)&Wl[kk + 1][c0];
            float4 w2 = *(float4*)&Wl[kk + 2][c0];
            float4 w3 = *(float4*)&Wl[kk + 3][c0];
#pragma unroll
            for (int i = 0; i < 4; ++i) {
                float4 a = *(float4*)&Al[r0 + i][kk];
                acc[i].x = fmaf(a.x, w0.x, acc[i].x);
                acc[i].y = fmaf(a.x, w0.y, acc[i].y);
                acc[i].z = fmaf(a.x, w0.z, acc[i].z);
                acc[i].w = fmaf(a.x, w0.w, acc[i].w);
                acc[i].x = fmaf(a.y, w1.x, acc[i].x);
                acc[i].y = fmaf(a.y, w1.y, acc[i].y);
                acc[i].z = fmaf(a.y, w1.z, acc[i].z);
                acc[i].w = fmaf(a.y, w1.w, acc[i].w);
                acc[i].x = fmaf(a.z, w2.x, acc[i].x);
                acc[i].y = fmaf(a.z, w2.y, acc[i].y);
                acc[i].z = fmaf(a.z, w2.z, acc[i].z);
                acc[i].w = fmaf(a.z, w2.w, acc[i].w);
                acc[i].x = fmaf(a.w, w3.x, acc[i].x);
                acc[i].y = fmaf(a.w, w3.y, acc[i].y);
                acc[i].z = fmaf(a.w, w3.z, acc[i].z);
                acc[i].w = fmaf(a.w, w3.w, acc[i].w);
            }
        }
        __syncthreads();
    }
    float4 bv = *(const float4*)&bias[c0];
#pragma unroll
    for (int i = 0; i < 4; ++i) {
        int row = m0 + r0 + i;
        if (row < M) {
            float* o = &out[(size_t)row * 64 + c0];
            o[0] = acc[i].x + bv.x;
            o[1] = acc[i].y + bv.y;
            o[2] = acc[i].z + bv.z;
            o[3] = acc[i].w + bv.w;
        }
    }
}

// ---------------- reconstruction loss (mask-gated gathers; fp8 rep, bf16 feat) ----------------
__global__ __launch_bounds__(256) void loss_kernel(const int* __restrict__ e0,
                                                   const int* __restrict__ e1,
                                                   const int* __restrict__ n0,
                                                   const int* __restrict__ n1,
                                                   const unsigned char* __restrict__ rep8,
                                                   const unsigned short* __restrict__ featB,
                                                   const float* __restrict__ ls,
                                                   float* accum, int E) {
    const int lane = threadIdx.x & 63;
    const int wline = threadIdx.x >> 6;
    const int gw = blockIdx.x * 4 + wline;
    const int nw = gridDim.x * 4;
    float ap = 0.f, an = 0.f, cp = 0.f, cn = 0.f;
    for (int e = gw; e < E; e += nw) {
        int a = e0[e], b = e1[e];
        int c = n0[e], d = n1[e];
        bool dop = a < b;           // wave-uniform
        bool don = c < d;           // wave-uniform
        if (dop) {
            unsigned int ra = *(const unsigned int*)&rep8[(size_t)a * 256 + lane * 4];
            unsigned int rb = *(const unsigned int*)&rep8[(size_t)b * 256 + lane * 4];
            const uint2 fa = *(const uint2*)&featB[(size_t)a * 256 + lane * 4];
            const uint2 fb = *(const uint2*)&featB[(size_t)b * 256 + lane * 4];
            floatx2 a01 = __builtin_amdgcn_cvt_pk_f32_fp8((int)ra, false);
            floatx2 a23 = __builtin_amdgcn_cvt_pk_f32_fp8((int)ra, true);
            floatx2 b01 = __builtin_amdgcn_cvt_pk_f32_fp8((int)rb, false);
            floatx2 b23 = __builtin_amdgcn_cvt_pk_f32_fp8((int)rb, true);
            float dp = a01.x * b01.x + a01.y * b01.y + a23.x * b23.x + a23.y * b23.y;
            float df = bfl(fa.x) * bfl(fb.x) + bfh(fa.x) * bfh(fb.x)
                     + bfl(fa.y) * bfl(fb.y) + bfh(fa.y) * bfh(fb.y);
#pragma unroll
            for (int o = 1; o < 64; o <<= 1) {
                dp += __shfl_xor(dp, o);
                df += __shfl_xor(df, o);
            }
            if (lane == 0) {
                float pw = fmaxf(dp, 0.f);
                float pos = THETA * df + (1.0f - THETA) * pw;
                float t = pos - ls[e];
                ap += t * t;
                cp += 1.f;
            }
        }
        if (don) {
            unsigned int rc = *(const unsigned int*)&rep8[(size_t)c * 256 + lane * 4];
            unsigned int rd = *(const unsigned int*)&rep8[(size_t)d * 256 + lane * 4];
            floatx2 c01 = __builtin_amdgcn_cvt_pk_f32_fp8((int)rc, false);
            floatx2 c23 = __builtin_amdgcn_cvt_pk_f32_fp8((int)rc, true);
            floatx2 d01 = __builtin_amdgcn_cvt_pk_f32_fp8((int)rd, false);
            floatx2 d23 = __builtin_amdgcn_cvt_pk_f32_fp8((int)rd, true);
            float dn = c01.x * d01.x + c01.y * d01.y + c23.x * d23.x + c23.y * d23.y;
#pragma unroll
            for (int o = 1; o < 64; o <<= 1) dn += __shfl_xor(dn, o);
            if (lane == 0) {
                float nwt = fmaxf(dn, 0.f);
                an += nwt * nwt;
                cn += 1.f;
            }
        }
    }
    __shared__ float s[4][4];
    if (lane == 0) {
        s[wline][0] = ap;
        s[wline][1] = an;
        s[wline][2] = cp;
        s[wline][3] = cn;
    }
    __syncthreads();
    if (threadIdx.x == 0) {
        float tp = 0.f, tn = 0.f, tcp = 0.f, tcn = 0.f;
#pragma unroll
        for (int w = 0; w < 4; ++w) {
            tp += s[w][0];
            tn += s[w][1];
            tcp += s[w][2];
            tcn += s[w][3];
        }
        unsafeAtomicAdd(&accum[0], tp);
        unsafeAtomicAdd(&accum[1], tn);
        unsafeAtomicAdd(&accum[2], tcp);
        unsafeAtomicAdd(&accum[3], tcn);
    }
}

__global__ void loss_final(const float* __restrict__ accum, float* __restrict__ out, int N) {
    out[0] = (accum[1] + accum[0]) * (float)N / (accum[3] + accum[2]);
}

// ---------------- launcher ----------------
extern "C" void kernel_launch(void* const* d_in, const int* in_sizes, int n_in,
                              void* d_out, int out_size, void* d_ws, size_t ws_size,
                              hipStream_t stream) {
    const int* edge = (const int*)d_in[0];
    const float* features = (const float*)d_in[1];
    const float* ls = (const float*)d_in[2];
    const int* nedge = (const int*)d_in[3];
    const float* W1 = (const float*)d_in[4];
    const float* b1 = (const float*)d_in[5];
    const float* W2 = (const float*)d_in[6];
    const float* b2 = (const float*)d_in[7];
    const float* Wy = (const float*)d_in[8];
    const float* by = (const float*)d_in[9];

    const int E = in_sizes[0] / 2;
    const int N = in_sizes[1] / FEAT;
    const int* e0 = edge;
    const int* e1 = edge + E;
    const int* n0 = nedge;
    const int* n1 = nedge + E;

    float* rep = (float*)d_out;          // [N,256] — also used as x1/x2 staging
    float* rec = rep + (size_t)N * 256;  // scalar
    float* y = rec + 1;                  // [N,64], 4B-aligned only

    // workspace carve-out
    char* base = (char*)d_ws;
    size_t off = 0;
    auto carve = [&](size_t bytes) -> void* {
        void* p = base + off;
        off += (bytes + 1023) & ~(size_t)1023;
        return p;
    };
    int* deg = (int*)carve((size_t)N * 4);
    float* dinv = (float*)carve((size_t)N * 4);
    float* accum = (float*)carve(16);
    int* rowptr = (int*)carve((size_t)(N + 1) * 4);
    int* cursor = (int*)carve((size_t)N * 4);
    int* colIdx = (int*)carve((size_t)E * 4);
    unsigned short* hB = (unsigned short*)carve((size_t)N * 256 * 2);
    unsigned short* featB = (unsigned short*)carve((size_t)N * 256 * 2);
    unsigned char* rep8 = (unsigned char*)carve((size_t)N * 256);

    // CSR build
    hipMemsetAsync(deg, 0, (size_t)N * 4, stream);
    deg_count<<<(E + 255) / 256, 256, 0, stream>>>(e0, E, deg);
    make_dinv<<<(N + 255) / 256, 256, 0, stream>>>(deg, dinv, N);
    scan_rowptr<<<1, 256, 0, stream>>>(deg, rowptr, cursor, N);
    bucket_edges<<<(E + 255) / 256, 256, 0, stream>>>(e0, e1, cursor, colIdx, E);

    const int gblk = (N + 63) / 64;
    const int wblk = (N + 3) / 4;
    const int n8 = N * 256 / 8;

    // bf16 feature table for the loss
    to_bf16<<<(n8 + 255) / 256, 256, 0, stream>>>(features, featB, n8);

    // conv1: h1B = bf16(features @ W1); x1 = relu(gather + selfloop + b1) -> rep region
    gemm256_obf16<<<gblk, 256, 0, stream>>>(features, W1, hB, N);
    spmm_gather_b16<<<wblk, 256, 0, stream>>>(rowptr, colIdx, hB, dinv, b1, rep, N, 1);

    // conv2: h2B = bf16(x1 @ W2); x2 = gather + selfloop + b2 -> rep (overwrites x1)
    gemm256_obf16<<<gblk, 256, 0, stream>>>(rep, W2, hB, N);
    spmm_gather_b16<<<wblk, 256, 0, stream>>>(rowptr, colIdx, hB, dinv, b2, rep, N, 0);

    // rep = l2norm(l2norm(x2)) in place
    l2norm2<<<wblk, 256, 0, stream>>>(rep, N);

    // fp8 rep table for the loss
    to_fp8<<<(n8 + 255) / 256, 256, 0, stream>>>(rep, rep8, n8);

    // y = rep @ Wy + by
    gemm_wy<<<gblk, 256, 0, stream>>>(rep, Wy, by, y, N);

    // loss
    hipMemsetAsync(accum, 0, 16, stream);
    loss_kernel<<<2048, 256, 0, stream>>>(e0, e1, n0, n1, rep8, featB, ls, accum, E);
    loss_final<<<1, 1, 0, stream>>>(accum, rec, N);
}

// Round 5
// 681.474 us; speedup vs baseline: 9.3696x; 1.2472x over previous
//
#include <hip/hip_runtime.h>
#include <hip/hip_bf16.h>

#define FEAT 256
#define HDIM 256
#define CDIM 64
#define THETA 0.5f
#define APAD 264  // A-tile LDS row stride in bf16 elems (256 + 8 -> +16B pad per row)

typedef float floatx2 __attribute__((ext_vector_type(2)));
typedef __attribute__((ext_vector_type(8))) short bf16x8;
typedef __attribute__((ext_vector_type(4))) float f32x4;

// ---------------- degree ----------------
__global__ __launch_bounds__(256) void deg_count(const int* __restrict__ e0, int E, int* deg) {
    int i = blockIdx.x * 256 + threadIdx.x;
    if (i < E) atomicAdd(&deg[e0[i]], 1);
}

__global__ __launch_bounds__(256) void make_dinv(const int* __restrict__ deg, float* __restrict__ dinv, int N) {
    int i = blockIdx.x * 256 + threadIdx.x;
    if (i < N) dinv[i] = rsqrtf((float)(deg[i] + 1));  // +1 self loop
}

// ---------------- single-block exclusive scan -> rowptr, cursor ----------------
__global__ __launch_bounds__(256) void scan_rowptr(const int* __restrict__ deg,
                                                   int* __restrict__ rowptr,
                                                   int* __restrict__ cursor, int N) {
    __shared__ int part[256];
    const int tid = threadIdx.x;
    const int chunk = (N + 255) / 256;
    const int s = tid * chunk;
    const int e = min(s + chunk, N);
    int sum = 0;
    for (int i = s; i < e; ++i) sum += deg[i];
    part[tid] = sum;
    __syncthreads();
#pragma unroll
    for (int off = 1; off < 256; off <<= 1) {
        int t = (tid >= off) ? part[tid - off] : 0;
        __syncthreads();
        part[tid] += t;
        __syncthreads();
    }
    int run = part[tid] - sum;  // exclusive prefix
    for (int i = s; i < e; ++i) {
        rowptr[i] = run;
        cursor[i] = run;
        run += deg[i];
    }
    if (tid == 255) rowptr[N] = run;
}

// ---------------- bucket edges into CSR ----------------
__global__ __launch_bounds__(256) void bucket_edges(const int* __restrict__ e0,
                                                    const int* __restrict__ e1,
                                                    int* cursor, int* __restrict__ colIdx, int E) {
    int i = blockIdx.x * 256 + threadIdx.x;
    if (i < E) {
        int r = e0[i];
        int pos = atomicAdd(&cursor[r], 1);
        colIdx[pos] = e1[i];
    }
}

// ---------------- conversions ----------------
__device__ __forceinline__ unsigned short f2bf(float f) {
    unsigned int u = __float_as_uint(f);
    u += 0x7fffu + ((u >> 16) & 1u);
    return (unsigned short)(u >> 16);
}
__device__ __forceinline__ float bfl(unsigned int u) { return __uint_as_float(u << 16); }
__device__ __forceinline__ float bfh(unsigned int u) { return __uint_as_float(u & 0xffff0000u); }

__global__ __launch_bounds__(256) void to_fp8(const float* __restrict__ src,
                                              unsigned char* __restrict__ dst, int n8) {
    int i = blockIdx.x * 256 + threadIdx.x;  // one thread per 8 floats
    if (i >= n8) return;
    float4 a = ((const float4*)src)[2 * i];
    float4 b = ((const float4*)src)[2 * i + 1];
    int w0 = __builtin_amdgcn_cvt_pk_fp8_f32(a.x, a.y, 0, false);
    w0 = __builtin_amdgcn_cvt_pk_fp8_f32(a.z, a.w, w0, true);
    int w1 = __builtin_amdgcn_cvt_pk_fp8_f32(b.x, b.y, 0, false);
    w1 = __builtin_amdgcn_cvt_pk_fp8_f32(b.z, b.w, w1, true);
    uint2 o;
    o.x = (unsigned int)w0;
    o.y = (unsigned int)w1;
    ((uint2*)dst)[i] = o;
}

// ---------------- W[256][256] fp32 -> Wt[n][k] bf16 ----------------
__global__ __launch_bounds__(256) void transposeW(const float* __restrict__ W,
                                                  unsigned short* __restrict__ Wt) {
    int k = blockIdx.x;
    int n = threadIdx.x;
    Wt[(size_t)n * 256 + k] = f2bf(W[(size_t)k * 256 + n]);
}

// ---------------- MFMA bf16 GEMM: out[M,256] = bf16( A_f32[M,256] @ W[256,256] ) ----------------
// Wt is the bf16 TRANSPOSED weight: Wt[n][k] = W[k][n]. B fragments load direct from global
// (L2-resident 128 KB); A tile staged fp32->bf16 in LDS with +16B row pad (uniform bank quads).
__global__ __launch_bounds__(256) void gemm_mfma(const float* __restrict__ A,
                                                 const unsigned short* __restrict__ Wt,
                                                 unsigned short* __restrict__ out, int M) {
    __shared__ unsigned short Al[64 * APAD];
    const int tid = threadIdx.x;
    const int m0 = blockIdx.x * 64;
    const int wv = tid >> 6;    // wave -> output cols [wv*64, wv*64+64)
    const int lane = tid & 63;

    // stage A: 64 rows x 256 cols bf16 = 2048 units of 16B; 8 units/thread
#pragma unroll
    for (int i = 0; i < 8; ++i) {
        int u = i * 256 + tid;
        int r = u >> 5;
        int c8 = (u & 31) * 8;
        int row = m0 + r;
        float4 v0, v1;
        if (row < M) {
            v0 = *(const float4*)&A[(size_t)row * 256 + c8];
            v1 = *(const float4*)&A[(size_t)row * 256 + c8 + 4];
        } else {
            v0 = make_float4(0.f, 0.f, 0.f, 0.f);
            v1 = v0;
        }
        uint4 o;
        o.x = (unsigned int)f2bf(v0.x) | ((unsigned int)f2bf(v0.y) << 16);
        o.y = (unsigned int)f2bf(v0.z) | ((unsigned int)f2bf(v0.w) << 16);
        o.z = (unsigned int)f2bf(v1.x) | ((unsigned int)f2bf(v1.y) << 16);
        o.w = (unsigned int)f2bf(v1.z) | ((unsigned int)f2bf(v1.w) << 16);
        *(uint4*)&Al[r * APAD + c8] = o;
    }
    __syncthreads();

    f32x4 acc[4][4] = {};
    const int r16 = lane & 15;
    const int kg8 = (lane >> 4) * 8;
    const unsigned short* wbase = Wt + ((size_t)(wv * 64 + r16)) * 256 + kg8;
    const unsigned short* abase = Al + r16 * APAD + kg8;

#pragma unroll
    for (int k0 = 0; k0 < 256; k0 += 32) {
        bf16x8 af[4], bfr[4];
#pragma unroll
        for (int mi = 0; mi < 4; ++mi)
            af[mi] = *(const bf16x8*)&abase[mi * 16 * APAD + k0];
#pragma unroll
        for (int ni = 0; ni < 4; ++ni)
            bfr[ni] = *(const bf16x8*)&wbase[ni * 16 * 256 + k0];
#pragma unroll
        for (int mi = 0; mi < 4; ++mi)
#pragma unroll
            for (int ni = 0; ni < 4; ++ni)
                acc[mi][ni] = __builtin_amdgcn_mfma_f32_16x16x32_bf16(af[mi], bfr[ni], acc[mi][ni], 0, 0, 0);
    }

    // epilogue: C/D layout col=lane&15, row=(lane>>4)*4+j
#pragma unroll
    for (int mi = 0; mi < 4; ++mi) {
        int rbase = m0 + mi * 16 + ((lane >> 4) << 2);
#pragma unroll
        for (int ni = 0; ni < 4; ++ni) {
            int col = (wv << 6) + (ni << 4) + (lane & 15);
#pragma unroll
            for (int j = 0; j < 4; ++j) {
                int row = rbase + j;
                if (row < M) out[(size_t)row * 256 + col] = f2bf(acc[mi][ni][j]);
            }
        }
    }
}

// ---------------- CSR gather SpMM (bf16 h table) fused with finalize ----------------
__global__ __launch_bounds__(256) void spmm_gather_b16(const int* __restrict__ rowptr,
                                                       const int* __restrict__ colIdx,
                                                       const unsigned short* __restrict__ h,
                                                       const float* __restrict__ dinv,
                                                       const float* __restrict__ bias,
                                                       float* __restrict__ out,
                                                       int N, int do_relu) {
    int row = (blockIdx.x * 256 + threadIdx.x) >> 6;
    int lane = threadIdx.x & 63;
    if (row >= N) return;
    int beg = rowptr[row];
    int end = rowptr[row + 1];
    float4 acc = make_float4(0.f, 0.f, 0.f, 0.f);
    int j = beg;
    for (; j + 3 < end; j += 4) {
        int c0 = colIdx[j + 0];
        int c1 = colIdx[j + 1];
        int c2 = colIdx[j + 2];
        int c3 = colIdx[j + 3];
        float w0 = dinv[c0], w1 = dinv[c1], w2 = dinv[c2], w3 = dinv[c3];
        uint2 h0 = *(const uint2*)&h[(size_t)c0 * 256 + lane * 4];
        uint2 h1 = *(const uint2*)&h[(size_t)c1 * 256 + lane * 4];
        uint2 h2 = *(const uint2*)&h[(size_t)c2 * 256 + lane * 4];
        uint2 h3 = *(const uint2*)&h[(size_t)c3 * 256 + lane * 4];
        acc.x = fmaf(w0, bfl(h0.x), acc.x); acc.y = fmaf(w0, bfh(h0.x), acc.y);
        acc.z = fmaf(w0, bfl(h0.y), acc.z); acc.w = fmaf(w0, bfh(h0.y), acc.w);
        acc.x = fmaf(w1, bfl(h1.x), acc.x); acc.y = fmaf(w1, bfh(h1.x), acc.y);
        acc.z = fmaf(w1, bfl(h1.y), acc.z); acc.w = fmaf(w1, bfh(h1.y), acc.w);
        acc.x = fmaf(w2, bfl(h2.x), acc.x); acc.y = fmaf(w2, bfh(h2.x), acc.y);
        acc.z = fmaf(w2, bfl(h2.y), acc.z); acc.w = fmaf(w2, bfh(h2.y), acc.w);
        acc.x = fmaf(w3, bfl(h3.x), acc.x); acc.y = fmaf(w3, bfh(h3.x), acc.y);
        acc.z = fmaf(w3, bfl(h3.y), acc.z); acc.w = fmaf(w3, bfh(h3.y), acc.w);
    }
    for (; j < end; ++j) {
        int c = colIdx[j];
        float w = dinv[c];
        uint2 hv = *(const uint2*)&h[(size_t)c * 256 + lane * 4];
        acc.x = fmaf(w, bfl(hv.x), acc.x); acc.y = fmaf(w, bfh(hv.x), acc.y);
        acc.z = fmaf(w, bfl(hv.y), acc.z); acc.w = fmaf(w, bfh(hv.y), acc.w);
    }
    float di = dinv[row];
    float s = di * di;
    uint2 hv = *(const uint2*)&h[(size_t)row * 256 + lane * 4];
    float4 bv = *(const float4*)&bias[lane * 4];
    float4 r;
    r.x = fmaf(di, acc.x, fmaf(s, bfl(hv.x), bv.x));
    r.y = fmaf(di, acc.y, fmaf(s, bfh(hv.x), bv.y));
    r.z = fmaf(di, acc.z, fmaf(s, bfl(hv.y), bv.z));
    r.w = fmaf(di, acc.w, fmaf(s, bfh(hv.y), bv.w));
    if (do_relu) {
        r.x = fmaxf(r.x, 0.f);
        r.y = fmaxf(r.y, 0.f);
        r.z = fmaxf(r.z, 0.f);
        r.w = fmaxf(r.w, 0.f);
    }
    *(float4*)&out[(size_t)row * 256 + lane * 4] = r;
}

// ---------------- double L2 normalize in place + fp8 table emit ----------------
__global__ __launch_bounds__(256) void l2norm2_f8(float* __restrict__ rep,
                                                  unsigned char* __restrict__ rep8, int N) {
    int gw = (blockIdx.x * 256 + threadIdx.x) >> 6;
    int lane = threadIdx.x & 63;
    if (gw >= N) return;
    float4 v = *(float4*)&rep[(size_t)gw * 256 + lane * 4];
    float ss = v.x * v.x + v.y * v.y + v.z * v.z + v.w * v.w;
#pragma unroll
    for (int o = 1; o < 64; o <<= 1) ss += __shfl_xor(ss, o);
    float inv = 1.0f / fmaxf(sqrtf(ss), 1e-12f);
    v.x *= inv; v.y *= inv; v.z *= inv; v.w *= inv;
    float ss2 = v.x * v.x + v.y * v.y + v.z * v.z + v.w * v.w;
#pragma unroll
    for (int o = 1; o < 64; o <<= 1) ss2 += __shfl_xor(ss2, o);
    float inv2 = 1.0f / fmaxf(sqrtf(ss2), 1e-12f);
    v.x *= inv2; v.y *= inv2; v.z *= inv2; v.w *= inv2;
    *(float4*)&rep[(size_t)gw * 256 + lane * 4] = v;
    int w = __builtin_amdgcn_cvt_pk_fp8_f32(v.x, v.y, 0, false);
    w = __builtin_amdgcn_cvt_pk_fp8_f32(v.z, v.w, w, true);
    *(unsigned int*)&rep8[(size_t)gw * 256 + lane * 4] = (unsigned int)w;
}

// ---------------- head GEMM: y[M,64] = rep[M,256] @ Wy[256,64] + by ----------------
__global__ __launch_bounds__(256) void gemm_wy(const float* __restrict__ A,
                                               const float* __restrict__ W,
                                               const float* __restrict__ bias,
                                               float* __restrict__ out, int M) {
    __shared__ float Wl[32][64];
    __shared__ float Al[64][40];
    const int tid = threadIdx.x;
    const int m0 = blockIdx.x * 64;
    const int c0 = (tid & 15) * 4;
    const int r0 = (tid >> 4) * 4;
    float4 acc[4];
#pragma unroll
    for (int i = 0; i < 4; ++i) acc[i] = make_float4(0.f, 0.f, 0.f, 0.f);

    for (int k0 = 0; k0 < 256; k0 += 32) {
#pragma unroll
        for (int i = 0; i < 2; ++i) {
            int j = i * 256 + tid;
            int kk = j >> 4;
            int c4 = (j & 15) * 4;
            float4 v = *(const float4*)&W[(size_t)(k0 + kk) * 64 + c4];
            *(float4*)&Wl[kk][c4] = v;
        }
#pragma unroll
        for (int i = 0; i < 2; ++i) {
            int j = i * 256 + tid;
            int r = j >> 3;
            int k4 = (j & 7) * 4;
            int row = m0 + r;
            float4 v = (row < M) ? *(const float4*)&A[(size_t)row * 256 + k0 + k4]
                                 : make_float4(0.f, 0.f, 0.f, 0.f);
            *(float4*)&Al[r][k4] = v;
        }
        __syncthreads();
#pragma unroll
        for (int kk = 0; kk < 32; kk += 4) {
            float4 w0 = *(float4*)&Wl[kk + 0][c0];
            float4 w1 = *(float4*)&Wl[kk + 1][c0];
            float4 w2 = *(float4*)&Wl[kk + 2][c0];
            float4 w3 = *(float4*)&Wl[kk + 3][c0];
#pragma unroll
            for (int i = 0; i < 4; ++i) {
                float4 a = *(float4*)&Al[r0 + i][kk];
                acc[i].x = fmaf(a.x, w0.x, acc[i].x);
                acc[i].y = fmaf(a.x, w0.y, acc[i].y);
                acc[i].z = fmaf(a.x, w0.z, acc[i].z);
                acc[i].w = fmaf(a.x, w0.w, acc[i].w);
                acc[i].x = fmaf(a.y, w1.x, acc[i].x);
                acc[i].y = fmaf(a.y, w1.y, acc[i].y);
                acc[i].z = fmaf(a.y, w1.z, acc[i].z);
                acc[i].w = fmaf(a.y, w1.w, acc[i].w);
                acc[i].x = fmaf(a.z, w2.x, acc[i].x);
                acc[i].y = fmaf(a.z, w2.y, acc[i].y);
                acc[i].z = fmaf(a.z, w2.z, acc[i].z);
                acc[i].w = fmaf(a.z, w2.w, acc[i].w);
                acc[i].x = fmaf(a.w, w3.x, acc[i].x);
                acc[i].y = fmaf(a.w, w3.y, acc[i].y);
                acc[i].z = fmaf(a.w, w3.z, acc[i].z);
                acc[i].w = fmaf(a.w, w3.w, acc[i].w);
            }
        }
        __syncthreads();
    }
    float4 bv = *(const float4*)&bias[c0];
#pragma unroll
    for (int i = 0; i < 4; ++i) {
        int row = m0 + r0 + i;
        if (row < M) {
            float* o = &out[(size_t)row * 64 + c0];
            o[0] = acc[i].x + bv.x;
            o[1] = acc[i].y + bv.y;
            o[2] = acc[i].z + bv.z;
            o[3] = acc[i].w + bv.w;
        }
    }
}

// ---------------- reconstruction loss (mask-gated; fp8 rep + fp8 feat) ----------------
__global__ __launch_bounds__(256) void loss_kernel(const int* __restrict__ e0,
                                                   const int* __restrict__ e1,
                                                   const int* __restrict__ n0,
                                                   const int* __restrict__ n1,
                                                   const unsigned char* __restrict__ rep8,
                                                   const unsigned char* __restrict__ feat8,
                                                   const float* __restrict__ ls,
                                                   float* accum, int E) {
    const int lane = threadIdx.x & 63;
    const int wline = threadIdx.x >> 6;
    const int gw = blockIdx.x * 4 + wline;
    const int nw = gridDim.x * 4;
    float ap = 0.f, an = 0.f, cp = 0.f, cn = 0.f;
    for (int e = gw; e < E; e += nw) {
        int a = e0[e], b = e1[e];
        int c = n0[e], d = n1[e];
        bool dop = a < b;  // wave-uniform
        bool don = c < d;  // wave-uniform
        if (dop) {
            unsigned int ra = *(const unsigned int*)&rep8[(size_t)a * 256 + lane * 4];
            unsigned int rb = *(const unsigned int*)&rep8[(size_t)b * 256 + lane * 4];
            unsigned int fa = *(const unsigned int*)&feat8[(size_t)a * 256 + lane * 4];
            unsigned int fb = *(const unsigned int*)&feat8[(size_t)b * 256 + lane * 4];
            floatx2 a01 = __builtin_amdgcn_cvt_pk_f32_fp8((int)ra, false);
            floatx2 a23 = __builtin_amdgcn_cvt_pk_f32_fp8((int)ra, true);
            floatx2 b01 = __builtin_amdgcn_cvt_pk_f32_fp8((int)rb, false);
            floatx2 b23 = __builtin_amdgcn_cvt_pk_f32_fp8((int)rb, true);
            floatx2 g01 = __builtin_amdgcn_cvt_pk_f32_fp8((int)fa, false);
            floatx2 g23 = __builtin_amdgcn_cvt_pk_f32_fp8((int)fa, true);
            floatx2 h01 = __builtin_amdgcn_cvt_pk_f32_fp8((int)fb, false);
            floatx2 h23 = __builtin_amdgcn_cvt_pk_f32_fp8((int)fb, true);
            float dp = a01.x * b01.x + a01.y * b01.y + a23.x * b23.x + a23.y * b23.y;
            float df = g01.x * h01.x + g01.y * h01.y + g23.x * h23.x + g23.y * h23.y;
#pragma unroll
            for (int o = 1; o < 64; o <<= 1) {
                dp += __shfl_xor(dp, o);
                df += __shfl_xor(df, o);
            }
            if (lane == 0) {
                float pw = fmaxf(dp, 0.f);
                float pos = THETA * df + (1.0f - THETA) * pw;
                float t = pos - ls[e];
                ap += t * t;
                cp += 1.f;
            }
        }
        if (don) {
            unsigned int rc = *(const unsigned int*)&rep8[(size_t)c * 256 + lane * 4];
            unsigned int rd = *(const unsigned int*)&rep8[(size_t)d * 256 + lane * 4];
            floatx2 c01 = __builtin_amdgcn_cvt_pk_f32_fp8((int)rc, false);
            floatx2 c23 = __builtin_amdgcn_cvt_pk_f32_fp8((int)rc, true);
            floatx2 d01 = __builtin_amdgcn_cvt_pk_f32_fp8((int)rd, false);
            floatx2 d23 = __builtin_amdgcn_cvt_pk_f32_fp8((int)rd, true);
            float dn = c01.x * d01.x + c01.y * d01.y + c23.x * d23.x + c23.y * d23.y;
#pragma unroll
            for (int o = 1; o < 64; o <<= 1) dn += __shfl_xor(dn, o);
            if (lane == 0) {
                float nwt = fmaxf(dn, 0.f);
                an += nwt * nwt;
                cn += 1.f;
            }
        }
    }
    __shared__ float s[4][4];
    if (lane == 0) {
        s[wline][0] = ap;
        s[wline][1] = an;
        s[wline][2] = cp;
        s[wline][3] = cn;
    }
    __syncthreads();
    if (threadIdx.x == 0) {
        float tp = 0.f, tn = 0.f, tcp = 0.f, tcn = 0.f;
#pragma unroll
        for (int w = 0; w < 4; ++w) {
            tp += s[w][0];
            tn += s[w][1];
            tcp += s[w][2];
            tcn += s[w][3];
        }
        unsafeAtomicAdd(&accum[0], tp);
        unsafeAtomicAdd(&accum[1], tn);
        unsafeAtomicAdd(&accum[2], tcp);
        unsafeAtomicAdd(&accum[3], tcn);
    }
}

__global__ void loss_final(const float* __restrict__ accum, float* __restrict__ out, int N) {
    out[0] = (accum[1] + accum[0]) * (float)N / (accum[3] + accum[2]);
}

// ---------------- launcher ----------------
extern "C" void kernel_launch(void* const* d_in, const int* in_sizes, int n_in,
                              void* d_out, int out_size, void* d_ws, size_t ws_size,
                              hipStream_t stream) {
    const int* edge = (const int*)d_in[0];
    const float* features = (const float*)d_in[1];
    const float* ls = (const float*)d_in[2];
    const int* nedge = (const int*)d_in[3];
    const float* W1 = (const float*)d_in[4];
    const float* b1 = (const float*)d_in[5];
    const float* W2 = (const float*)d_in[6];
    const float* b2 = (const float*)d_in[7];
    const float* Wy = (const float*)d_in[8];
    const float* by = (const float*)d_in[9];

    const int E = in_sizes[0] / 2;
    const int N = in_sizes[1] / FEAT;
    const int* e0 = edge;
    const int* e1 = edge + E;
    const int* n0 = nedge;
    const int* n1 = nedge + E;

    float* rep = (float*)d_out;          // [N,256] — also x1/x2 staging
    float* rec = rep + (size_t)N * 256;  // scalar
    float* y = rec + 1;                  // [N,64], 4B-aligned only

    // workspace carve-out
    char* base = (char*)d_ws;
    size_t off = 0;
    auto carve = [&](size_t bytes) -> void* {
        void* p = base + off;
        off += (bytes + 1023) & ~(size_t)1023;
        return p;
    };
    int* deg = (int*)carve((size_t)N * 4);
    float* dinv = (float*)carve((size_t)N * 4);
    float* accum = (float*)carve(16);
    int* rowptr = (int*)carve((size_t)(N + 1) * 4);
    int* cursor = (int*)carve((size_t)N * 4);
    int* colIdx = (int*)carve((size_t)E * 4);
    unsigned short* hB = (unsigned short*)carve((size_t)N * 256 * 2);
    unsigned char* feat8 = (unsigned char*)carve((size_t)N * 256);
    unsigned char* rep8 = (unsigned char*)carve((size_t)N * 256);
    unsigned short* Wt1 = (unsigned short*)carve(256 * 256 * 2);
    unsigned short* Wt2 = (unsigned short*)carve(256 * 256 * 2);

    // CSR build
    hipMemsetAsync(deg, 0, (size_t)N * 4, stream);
    deg_count<<<(E + 255) / 256, 256, 0, stream>>>(e0, E, deg);
    make_dinv<<<(N + 255) / 256, 256, 0, stream>>>(deg, dinv, N);
    scan_rowptr<<<1, 256, 0, stream>>>(deg, rowptr, cursor, N);
    bucket_edges<<<(E + 255) / 256, 256, 0, stream>>>(e0, e1, cursor, colIdx, E);

    const int gblk = (N + 63) / 64;
    const int wblk = (N + 3) / 4;
    const int n8 = N * 256 / 8;

    // loss-side fp8 feature table; bf16-transposed weights
    to_fp8<<<(n8 + 255) / 256, 256, 0, stream>>>(features, feat8, n8);
    transposeW<<<256, 256, 0, stream>>>(W1, Wt1);
    transposeW<<<256, 256, 0, stream>>>(W2, Wt2);

    // conv1: hB = bf16(features @ W1) via MFMA; x1 = relu(gather + selfloop + b1) -> rep
    gemm_mfma<<<gblk, 256, 0, stream>>>(features, Wt1, hB, N);
    spmm_gather_b16<<<wblk, 256, 0, stream>>>(rowptr, colIdx, hB, dinv, b1, rep, N, 1);

    // conv2: hB = bf16(x1 @ W2) via MFMA; x2 = gather + selfloop + b2 -> rep
    gemm_mfma<<<gblk, 256, 0, stream>>>(rep, Wt2, hB, N);
    spmm_gather_b16<<<wblk, 256, 0, stream>>>(rowptr, colIdx, hB, dinv, b2, rep, N, 0);

    // rep = l2norm(l2norm(x2)) in place + fp8 table
    l2norm2_f8<<<wblk, 256, 0, stream>>>(rep, rep8, N);

    // y = rep @ Wy + by
    gemm_wy<<<gblk, 256, 0, stream>>>(rep, Wy, by, y, N);

    // loss
    hipMemsetAsync(accum, 0, 16, stream);
    loss_kernel<<<2048, 256, 0, stream>>>(e0, e1, n0, n1, rep8, feat8, ls, accum, E);
    loss_final<<<1, 1, 0, stream>>>(accum, rec, N);
}

// Round 6
// 631.908 us; speedup vs baseline: 10.1046x; 1.0784x over previous
//
#include <hip/hip_runtime.h>
#include <hip/hip_bf16.h>

#define FEAT 256
#define HDIM 256
#define CDIM 64
#define THETA 0.5f
#define APAD 264  // A-tile LDS row stride in bf16 elems (256 + 8 -> +16B pad per row)

typedef float floatx2 __attribute__((ext_vector_type(2)));
typedef __attribute__((ext_vector_type(8))) short bf16x8;
typedef __attribute__((ext_vector_type(4))) float f32x4;

// ---------------- degree ----------------
__global__ __launch_bounds__(256) void deg_count(const int* __restrict__ e0, int E, int* deg) {
    int i = blockIdx.x * 256 + threadIdx.x;
    if (i < E) atomicAdd(&deg[e0[i]], 1);
}

__global__ __launch_bounds__(256) void make_dinv(const int* __restrict__ deg, float* __restrict__ dinv, int N) {
    int i = blockIdx.x * 256 + threadIdx.x;
    if (i < N) dinv[i] = rsqrtf((float)(deg[i] + 1));  // +1 self loop
}

// ---------------- single-block exclusive scan -> rowptr, cursor ----------------
__global__ __launch_bounds__(256) void scan_rowptr(const int* __restrict__ deg,
                                                   int* __restrict__ rowptr,
                                                   int* __restrict__ cursor, int N) {
    __shared__ int part[256];
    const int tid = threadIdx.x;
    const int chunk = (N + 255) / 256;
    const int s = tid * chunk;
    const int e = min(s + chunk, N);
    int sum = 0;
    for (int i = s; i < e; ++i) sum += deg[i];
    part[tid] = sum;
    __syncthreads();
#pragma unroll
    for (int off = 1; off < 256; off <<= 1) {
        int t = (tid >= off) ? part[tid - off] : 0;
        __syncthreads();
        part[tid] += t;
        __syncthreads();
    }
    int run = part[tid] - sum;  // exclusive prefix
    for (int i = s; i < e; ++i) {
        rowptr[i] = run;
        cursor[i] = run;
        run += deg[i];
    }
    if (tid == 255) rowptr[N] = run;
}

// ---------------- bucket edges into CSR ----------------
__global__ __launch_bounds__(256) void bucket_edges(const int* __restrict__ e0,
                                                    const int* __restrict__ e1,
                                                    int* cursor, int* __restrict__ colIdx, int E) {
    int i = blockIdx.x * 256 + threadIdx.x;
    if (i < E) {
        int r = e0[i];
        int pos = atomicAdd(&cursor[r], 1);
        colIdx[pos] = e1[i];
    }
}

// ---------------- conversions ----------------
__device__ __forceinline__ unsigned short f2bf(float f) {
    unsigned int u = __float_as_uint(f);
    u += 0x7fffu + ((u >> 16) & 1u);
    return (unsigned short)(u >> 16);
}
__device__ __forceinline__ float bfl(unsigned int u) { return __uint_as_float(u << 16); }
__device__ __forceinline__ float bfh(unsigned int u) { return __uint_as_float(u & 0xffff0000u); }

__global__ __launch_bounds__(256) void to_fp8(const float* __restrict__ src,
                                              unsigned char* __restrict__ dst, int n8) {
    int i = blockIdx.x * 256 + threadIdx.x;  // one thread per 8 floats
    if (i >= n8) return;
    float4 a = ((const float4*)src)[2 * i];
    float4 b = ((const float4*)src)[2 * i + 1];
    int w0 = __builtin_amdgcn_cvt_pk_fp8_f32(a.x, a.y, 0, false);
    w0 = __builtin_amdgcn_cvt_pk_fp8_f32(a.z, a.w, w0, true);
    int w1 = __builtin_amdgcn_cvt_pk_fp8_f32(b.x, b.y, 0, false);
    w1 = __builtin_amdgcn_cvt_pk_fp8_f32(b.z, b.w, w1, true);
    uint2 o;
    o.x = (unsigned int)w0;
    o.y = (unsigned int)w1;
    ((uint2*)dst)[i] = o;
}

// ---------------- W[256][256] fp32 -> Wt[n][k] bf16 ----------------
__global__ __launch_bounds__(256) void transposeW(const float* __restrict__ W,
                                                  unsigned short* __restrict__ Wt) {
    int k = blockIdx.x;
    int n = threadIdx.x;
    Wt[(size_t)n * 256 + k] = f2bf(W[(size_t)k * 256 + n]);
}

// ---------------- Wy[256][64] fp32 -> WyT[64][256] bf16 ----------------
__global__ __launch_bounds__(64) void transposeWy(const float* __restrict__ W,
                                                  unsigned short* __restrict__ Wt) {
    int k = blockIdx.x;   // 0..255
    int n = threadIdx.x;  // 0..63
    Wt[(size_t)n * 256 + k] = f2bf(W[(size_t)k * 64 + n]);
}

// ---------------- MFMA bf16 GEMM: out[M,256] = bf16( A_f32[M,256] @ W[256,256] ) ----------------
__global__ __launch_bounds__(256) void gemm_mfma(const float* __restrict__ A,
                                                 const unsigned short* __restrict__ Wt,
                                                 unsigned short* __restrict__ out, int M) {
    __shared__ unsigned short Al[64 * APAD];
    const int tid = threadIdx.x;
    const int m0 = blockIdx.x * 64;
    const int wv = tid >> 6;  // wave -> output cols [wv*64, wv*64+64)
    const int lane = tid & 63;

    // stage A: 64 rows x 256 cols bf16 = 2048 units of 16B; 8 units/thread
#pragma unroll
    for (int i = 0; i < 8; ++i) {
        int u = i * 256 + tid;
        int r = u >> 5;
        int c8 = (u & 31) * 8;
        int row = m0 + r;
        float4 v0, v1;
        if (row < M) {
            v0 = *(const float4*)&A[(size_t)row * 256 + c8];
            v1 = *(const float4*)&A[(size_t)row * 256 + c8 + 4];
        } else {
            v0 = make_float4(0.f, 0.f, 0.f, 0.f);
            v1 = v0;
        }
        uint4 o;
        o.x = (unsigned int)f2bf(v0.x) | ((unsigned int)f2bf(v0.y) << 16);
        o.y = (unsigned int)f2bf(v0.z) | ((unsigned int)f2bf(v0.w) << 16);
        o.z = (unsigned int)f2bf(v1.x) | ((unsigned int)f2bf(v1.y) << 16);
        o.w = (unsigned int)f2bf(v1.z) | ((unsigned int)f2bf(v1.w) << 16);
        *(uint4*)&Al[r * APAD + c8] = o;
    }
    __syncthreads();

    f32x4 acc[4][4] = {};
    const int r16 = lane & 15;
    const int kg8 = (lane >> 4) * 8;
    const unsigned short* wbase = Wt + ((size_t)(wv * 64 + r16)) * 256 + kg8;
    const unsigned short* abase = Al + r16 * APAD + kg8;

#pragma unroll
    for (int k0 = 0; k0 < 256; k0 += 32) {
        bf16x8 af[4], bfr[4];
#pragma unroll
        for (int mi = 0; mi < 4; ++mi)
            af[mi] = *(const bf16x8*)&abase[mi * 16 * APAD + k0];
#pragma unroll
        for (int ni = 0; ni < 4; ++ni)
            bfr[ni] = *(const bf16x8*)&wbase[ni * 16 * 256 + k0];
#pragma unroll
        for (int mi = 0; mi < 4; ++mi)
#pragma unroll
            for (int ni = 0; ni < 4; ++ni)
                acc[mi][ni] = __builtin_amdgcn_mfma_f32_16x16x32_bf16(af[mi], bfr[ni], acc[mi][ni], 0, 0, 0);
    }

    // epilogue: C/D layout col=lane&15, row=(lane>>4)*4+j
#pragma unroll
    for (int mi = 0; mi < 4; ++mi) {
        int rbase = m0 + mi * 16 + ((lane >> 4) << 2);
#pragma unroll
        for (int ni = 0; ni < 4; ++ni) {
            int col = (wv << 6) + (ni << 4) + (lane & 15);
#pragma unroll
            for (int j = 0; j < 4; ++j) {
                int row = rbase + j;
                if (row < M) out[(size_t)row * 256 + col] = f2bf(acc[mi][ni][j]);
            }
        }
    }
}

// ---------------- MFMA head GEMM: y[M,64] = rep[M,256] @ Wy + by ----------------
// WyT[64][256] bf16 transposed weight. out is only 4B-aligned -> scalar stores.
__global__ __launch_bounds__(256) void gemm_wy_mfma(const float* __restrict__ A,
                                                    const unsigned short* __restrict__ WyT,
                                                    const float* __restrict__ bias,
                                                    float* __restrict__ out, int M) {
    __shared__ unsigned short Al[64 * APAD];
    const int tid = threadIdx.x;
    const int m0 = blockIdx.x * 64;
    const int wv = tid >> 6;  // wave -> output cols [wv*16, wv*16+16)
    const int lane = tid & 63;

#pragma unroll
    for (int i = 0; i < 8; ++i) {
        int u = i * 256 + tid;
        int r = u >> 5;
        int c8 = (u & 31) * 8;
        int row = m0 + r;
        float4 v0, v1;
        if (row < M) {
            v0 = *(const float4*)&A[(size_t)row * 256 + c8];
            v1 = *(const float4*)&A[(size_t)row * 256 + c8 + 4];
        } else {
            v0 = make_float4(0.f, 0.f, 0.f, 0.f);
            v1 = v0;
        }
        uint4 o;
        o.x = (unsigned int)f2bf(v0.x) | ((unsigned int)f2bf(v0.y) << 16);
        o.y = (unsigned int)f2bf(v0.z) | ((unsigned int)f2bf(v0.w) << 16);
        o.z = (unsigned int)f2bf(v1.x) | ((unsigned int)f2bf(v1.y) << 16);
        o.w = (unsigned int)f2bf(v1.z) | ((unsigned int)f2bf(v1.w) << 16);
        *(uint4*)&Al[r * APAD + c8] = o;
    }
    __syncthreads();

    f32x4 acc[4] = {};
    const int r16 = lane & 15;
    const int kg8 = (lane >> 4) * 8;
    const unsigned short* wbase = WyT + ((size_t)(wv * 16 + r16)) * 256 + kg8;
    const unsigned short* abase = Al + r16 * APAD + kg8;

#pragma unroll
    for (int k0 = 0; k0 < 256; k0 += 32) {
        bf16x8 bfr = *(const bf16x8*)&wbase[k0];
#pragma unroll
        for (int mi = 0; mi < 4; ++mi) {
            bf16x8 af = *(const bf16x8*)&abase[mi * 16 * APAD + k0];
            acc[mi] = __builtin_amdgcn_mfma_f32_16x16x32_bf16(af, bfr, acc[mi], 0, 0, 0);
        }
    }

    int col = (wv << 4) + (lane & 15);
    float bv = bias[col];
#pragma unroll
    for (int mi = 0; mi < 4; ++mi) {
        int rbase = m0 + mi * 16 + ((lane >> 4) << 2);
#pragma unroll
        for (int j = 0; j < 4; ++j) {
            int row = rbase + j;
            if (row < M) out[(size_t)row * 64 + col] = acc[mi][j] + bv;
        }
    }
}

// ---------------- CSR gather SpMM (bf16 h table) fused with finalize ----------------
__global__ __launch_bounds__(256) void spmm_gather_b16(const int* __restrict__ rowptr,
                                                       const int* __restrict__ colIdx,
                                                       const unsigned short* __restrict__ h,
                                                       const float* __restrict__ dinv,
                                                       const float* __restrict__ bias,
                                                       float* __restrict__ out,
                                                       int N, int do_relu) {
    int row = (blockIdx.x * 256 + threadIdx.x) >> 6;
    int lane = threadIdx.x & 63;
    if (row >= N) return;
    int beg = rowptr[row];
    int end = rowptr[row + 1];
    float4 acc = make_float4(0.f, 0.f, 0.f, 0.f);
    int j = beg;
    for (; j + 3 < end; j += 4) {
        int c0 = colIdx[j + 0];
        int c1 = colIdx[j + 1];
        int c2 = colIdx[j + 2];
        int c3 = colIdx[j + 3];
        float w0 = dinv[c0], w1 = dinv[c1], w2 = dinv[c2], w3 = dinv[c3];
        uint2 h0 = *(const uint2*)&h[(size_t)c0 * 256 + lane * 4];
        uint2 h1 = *(const uint2*)&h[(size_t)c1 * 256 + lane * 4];
        uint2 h2 = *(const uint2*)&h[(size_t)c2 * 256 + lane * 4];
        uint2 h3 = *(const uint2*)&h[(size_t)c3 * 256 + lane * 4];
        acc.x = fmaf(w0, bfl(h0.x), acc.x); acc.y = fmaf(w0, bfh(h0.x), acc.y);
        acc.z = fmaf(w0, bfl(h0.y), acc.z); acc.w = fmaf(w0, bfh(h0.y), acc.w);
        acc.x = fmaf(w1, bfl(h1.x), acc.x); acc.y = fmaf(w1, bfh(h1.x), acc.y);
        acc.z = fmaf(w1, bfl(h1.y), acc.z); acc.w = fmaf(w1, bfh(h1.y), acc.w);
        acc.x = fmaf(w2, bfl(h2.x), acc.x); acc.y = fmaf(w2, bfh(h2.x), acc.y);
        acc.z = fmaf(w2, bfl(h2.y), acc.z); acc.w = fmaf(w2, bfh(h2.y), acc.w);
        acc.x = fmaf(w3, bfl(h3.x), acc.x); acc.y = fmaf(w3, bfh(h3.x), acc.y);
        acc.z = fmaf(w3, bfl(h3.y), acc.z); acc.w = fmaf(w3, bfh(h3.y), acc.w);
    }
    for (; j < end; ++j) {
        int c = colIdx[j];
        float w = dinv[c];
        uint2 hv = *(const uint2*)&h[(size_t)c * 256 + lane * 4];
        acc.x = fmaf(w, bfl(hv.x), acc.x); acc.y = fmaf(w, bfh(hv.x), acc.y);
        acc.z = fmaf(w, bfl(hv.y), acc.z); acc.w = fmaf(w, bfh(hv.y), acc.w);
    }
    float di = dinv[row];
    float s = di * di;
    uint2 hv = *(const uint2*)&h[(size_t)row * 256 + lane * 4];
    float4 bv = *(const float4*)&bias[lane * 4];
    float4 r;
    r.x = fmaf(di, acc.x, fmaf(s, bfl(hv.x), bv.x));
    r.y = fmaf(di, acc.y, fmaf(s, bfh(hv.x), bv.y));
    r.z = fmaf(di, acc.z, fmaf(s, bfl(hv.y), bv.z));
    r.w = fmaf(di, acc.w, fmaf(s, bfh(hv.y), bv.w));
    if (do_relu) {
        r.x = fmaxf(r.x, 0.f);
        r.y = fmaxf(r.y, 0.f);
        r.z = fmaxf(r.z, 0.f);
        r.w = fmaxf(r.w, 0.f);
    }
    *(float4*)&out[(size_t)row * 256 + lane * 4] = r;
}

// ---------------- double L2 normalize in place + fp8 table emit ----------------
__global__ __launch_bounds__(256) void l2norm2_f8(float* __restrict__ rep,
                                                  unsigned char* __restrict__ rep8, int N) {
    int gw = (blockIdx.x * 256 + threadIdx.x) >> 6;
    int lane = threadIdx.x & 63;
    if (gw >= N) return;
    float4 v = *(float4*)&rep[(size_t)gw * 256 + lane * 4];
    float ss = v.x * v.x + v.y * v.y + v.z * v.z + v.w * v.w;
#pragma unroll
    for (int o = 1; o < 64; o <<= 1) ss += __shfl_xor(ss, o);
    float inv = 1.0f / fmaxf(sqrtf(ss), 1e-12f);
    v.x *= inv; v.y *= inv; v.z *= inv; v.w *= inv;
    float ss2 = v.x * v.x + v.y * v.y + v.z * v.z + v.w * v.w;
#pragma unroll
    for (int o = 1; o < 64; o <<= 1) ss2 += __shfl_xor(ss2, o);
    float inv2 = 1.0f / fmaxf(sqrtf(ss2), 1e-12f);
    v.x *= inv2; v.y *= inv2; v.z *= inv2; v.w *= inv2;
    *(float4*)&rep[(size_t)gw * 256 + lane * 4] = v;
    int w = __builtin_amdgcn_cvt_pk_fp8_f32(v.x, v.y, 0, false);
    w = __builtin_amdgcn_cvt_pk_fp8_f32(v.z, v.w, w, true);
    *(unsigned int*)&rep8[(size_t)gw * 256 + lane * 4] = (unsigned int)w;
}

// ---------------- loss helpers ----------------
__device__ __forceinline__ float dot16fp8(uint4 x, uint4 y) {
    float s = 0.f;
    const unsigned int xs[4] = {x.x, x.y, x.z, x.w};
    const unsigned int ys[4] = {y.x, y.y, y.z, y.w};
#pragma unroll
    for (int i = 0; i < 4; ++i) {
        floatx2 xl = __builtin_amdgcn_cvt_pk_f32_fp8((int)xs[i], false);
        floatx2 xh = __builtin_amdgcn_cvt_pk_f32_fp8((int)xs[i], true);
        floatx2 yl = __builtin_amdgcn_cvt_pk_f32_fp8((int)ys[i], false);
        floatx2 yh = __builtin_amdgcn_cvt_pk_f32_fp8((int)ys[i], true);
        s += xl.x * yl.x + xl.y * yl.y + xh.x * yh.x + xh.y * yh.y;
    }
    return s;
}

// ---------------- reconstruction loss: one edge-pair per 16-lane group ----------------
__global__ __launch_bounds__(256) void loss_kernel(const int* __restrict__ e0,
                                                   const int* __restrict__ e1,
                                                   const int* __restrict__ n0,
                                                   const int* __restrict__ n1,
                                                   const unsigned char* __restrict__ rep8,
                                                   const unsigned char* __restrict__ feat8,
                                                   const float* __restrict__ ls,
                                                   float* accum, int E) {
    const int tid = threadIdx.x;
    const int l16 = tid & 15;                       // slot within group (16B each)
    const int grp = (blockIdx.x * 256 + tid) >> 4;  // global group id
    const int ngrp = gridDim.x * 16;
    float ap = 0.f, an = 0.f, cp = 0.f, cn = 0.f;
    for (int e = grp; e < E; e += ngrp) {
        int a = e0[e], b = e1[e];
        int c = n0[e], d = n1[e];
        bool dop = a < b;  // uniform within group
        bool don = c < d;
        if (dop) {
            uint4 ra = *(const uint4*)&rep8[(size_t)a * 256 + l16 * 16];
            uint4 rb = *(const uint4*)&rep8[(size_t)b * 256 + l16 * 16];
            uint4 fa = *(const uint4*)&feat8[(size_t)a * 256 + l16 * 16];
            uint4 fb = *(const uint4*)&feat8[(size_t)b * 256 + l16 * 16];
            float dp = dot16fp8(ra, rb);
            float df = dot16fp8(fa, fb);
#pragma unroll
            for (int o = 1; o < 16; o <<= 1) {
                dp += __shfl_xor(dp, o);
                df += __shfl_xor(df, o);
            }
            if (l16 == 0) {
                float pw = fmaxf(dp, 0.f);
                float pos = THETA * df + (1.0f - THETA) * pw;
                float t = pos - ls[e];
                ap += t * t;
                cp += 1.f;
            }
        }
        if (don) {
            uint4 rc = *(const uint4*)&rep8[(size_t)c * 256 + l16 * 16];
            uint4 rd = *(const uint4*)&rep8[(size_t)d * 256 + l16 * 16];
            float dn = dot16fp8(rc, rd);
#pragma unroll
            for (int o = 1; o < 16; o <<= 1) dn += __shfl_xor(dn, o);
            if (l16 == 0) {
                float nwt = fmaxf(dn, 0.f);
                an += nwt * nwt;
                cn += 1.f;
            }
        }
    }
    // wave-level reduce (partials live on lanes with l16==0; others are 0)
#pragma unroll
    for (int o = 1; o < 64; o <<= 1) {
        ap += __shfl_xor(ap, o);
        an += __shfl_xor(an, o);
        cp += __shfl_xor(cp, o);
        cn += __shfl_xor(cn, o);
    }
    __shared__ float s[4][4];
    const int wline = tid >> 6;
    if ((tid & 63) == 0) {
        s[wline][0] = ap;
        s[wline][1] = an;
        s[wline][2] = cp;
        s[wline][3] = cn;
    }
    __syncthreads();
    if (tid == 0) {
        float tp = 0.f, tn = 0.f, tcp = 0.f, tcn = 0.f;
#pragma unroll
        for (int w = 0; w < 4; ++w) {
            tp += s[w][0];
            tn += s[w][1];
            tcp += s[w][2];
            tcn += s[w][3];
        }
        unsafeAtomicAdd(&accum[0], tp);
        unsafeAtomicAdd(&accum[1], tn);
        unsafeAtomicAdd(&accum[2], tcp);
        unsafeAtomicAdd(&accum[3], tcn);
    }
}

__global__ void loss_final(const float* __restrict__ accum, float* __restrict__ out, int N) {
    out[0] = (accum[1] + accum[0]) * (float)N / (accum[3] + accum[2]);
}

// ---------------- launcher ----------------
extern "C" void kernel_launch(void* const* d_in, const int* in_sizes, int n_in,
                              void* d_out, int out_size, void* d_ws, size_t ws_size,
                              hipStream_t stream) {
    const int* edge = (const int*)d_in[0];
    const float* features = (const float*)d_in[1];
    const float* ls = (const float*)d_in[2];
    const int* nedge = (const int*)d_in[3];
    const float* W1 = (const float*)d_in[4];
    const float* b1 = (const float*)d_in[5];
    const float* W2 = (const float*)d_in[6];
    const float* b2 = (const float*)d_in[7];
    const float* Wy = (const float*)d_in[8];
    const float* by = (const float*)d_in[9];

    const int E = in_sizes[0] / 2;
    const int N = in_sizes[1] / FEAT;
    const int* e0 = edge;
    const int* e1 = edge + E;
    const int* n0 = nedge;
    const int* n1 = nedge + E;

    float* rep = (float*)d_out;          // [N,256] — also x1/x2 staging
    float* rec = rep + (size_t)N * 256;  // scalar
    float* y = rec + 1;                  // [N,64], 4B-aligned only

    // workspace carve-out
    char* base = (char*)d_ws;
    size_t off = 0;
    auto carve = [&](size_t bytes) -> void* {
        void* p = base + off;
        off += (bytes + 1023) & ~(size_t)1023;
        return p;
    };
    int* deg = (int*)carve((size_t)N * 4);
    float* dinv = (float*)carve((size_t)N * 4);
    float* accum = (float*)carve(16);
    int* rowptr = (int*)carve((size_t)(N + 1) * 4);
    int* cursor = (int*)carve((size_t)N * 4);
    int* colIdx = (int*)carve((size_t)E * 4);
    unsigned short* hB = (unsigned short*)carve((size_t)N * 256 * 2);
    unsigned char* feat8 = (unsigned char*)carve((size_t)N * 256);
    unsigned char* rep8 = (unsigned char*)carve((size_t)N * 256);
    unsigned short* Wt1 = (unsigned short*)carve(256 * 256 * 2);
    unsigned short* Wt2 = (unsigned short*)carve(256 * 256 * 2);
    unsigned short* WyT = (unsigned short*)carve(64 * 256 * 2);

    // CSR build
    hipMemsetAsync(deg, 0, (size_t)N * 4, stream);
    deg_count<<<(E + 255) / 256, 256, 0, stream>>>(e0, E, deg);
    make_dinv<<<(N + 255) / 256, 256, 0, stream>>>(deg, dinv, N);
    scan_rowptr<<<1, 256, 0, stream>>>(deg, rowptr, cursor, N);
    bucket_edges<<<(E + 255) / 256, 256, 0, stream>>>(e0, e1, cursor, colIdx, E);

    const int gblk = (N + 63) / 64;
    const int wblk = (N + 3) / 4;
    const int n8 = N * 256 / 8;

    // loss-side fp8 feature table; bf16-transposed weights
    to_fp8<<<(n8 + 255) / 256, 256, 0, stream>>>(features, feat8, n8);
    transposeW<<<256, 256, 0, stream>>>(W1, Wt1);
    transposeW<<<256, 256, 0, stream>>>(W2, Wt2);
    transposeWy<<<256, 64, 0, stream>>>(Wy, WyT);

    // conv1: hB = bf16(features @ W1) via MFMA; x1 = relu(gather + selfloop + b1) -> rep
    gemm_mfma<<<gblk, 256, 0, stream>>>(features, Wt1, hB, N);
    spmm_gather_b16<<<wblk, 256, 0, stream>>>(rowptr, colIdx, hB, dinv, b1, rep, N, 1);

    // conv2: hB = bf16(x1 @ W2) via MFMA; x2 = gather + selfloop + b2 -> rep
    gemm_mfma<<<gblk, 256, 0, stream>>>(rep, Wt2, hB, N);
    spmm_gather_b16<<<wblk, 256, 0, stream>>>(rowptr, colIdx, hB, dinv, b2, rep, N, 0);

    // rep = l2norm(l2norm(x2)) in place + fp8 table
    l2norm2_f8<<<wblk, 256, 0, stream>>>(rep, rep8, N);

    // y = rep @ Wy + by (MFMA)
    gemm_wy_mfma<<<gblk, 256, 0, stream>>>(rep, WyT, by, y, N);

    // loss
    hipMemsetAsync(accum, 0, 16, stream);
    loss_kernel<<<2048, 256, 0, stream>>>(e0, e1, n0, n1, rep8, feat8, ls, accum, E);
    loss_final<<<1, 1, 0, stream>>>(accum, rec, N);
}

// Round 7
// 553.567 us; speedup vs baseline: 11.5346x; 1.1415x over previous
//
#include <hip/hip_runtime.h>
#include <hip/hip_bf16.h>

#define FEAT 256
#define HDIM 256
#define CDIM 64
#define THETA 0.5f
#define APAD 264  // A-tile LDS row stride in bf16 elems (256 + 8 -> +16B pad per row)

typedef float floatx2 __attribute__((ext_vector_type(2)));
typedef __attribute__((ext_vector_type(8))) short bf16x8;
typedef __attribute__((ext_vector_type(4))) float f32x4;

// ---------------- degree ----------------
__global__ __launch_bounds__(256) void deg_count(const int* __restrict__ e0, int E, int* deg) {
    int i = blockIdx.x * 256 + threadIdx.x;
    if (i < E) atomicAdd(&deg[e0[i]], 1);
}

__global__ __launch_bounds__(256) void make_dinv(const int* __restrict__ deg, float* __restrict__ dinv, int N) {
    int i = blockIdx.x * 256 + threadIdx.x;
    if (i < N) dinv[i] = rsqrtf((float)(deg[i] + 1));  // +1 self loop
}

// ---------------- single-block exclusive scan -> rowptr, cursor ----------------
__global__ __launch_bounds__(256) void scan_rowptr(const int* __restrict__ deg,
                                                   int* __restrict__ rowptr,
                                                   int* __restrict__ cursor, int N) {
    __shared__ int part[256];
    const int tid = threadIdx.x;
    const int chunk = (N + 255) / 256;
    const int s = tid * chunk;
    const int e = min(s + chunk, N);
    int sum = 0;
    for (int i = s; i < e; ++i) sum += deg[i];
    part[tid] = sum;
    __syncthreads();
#pragma unroll
    for (int off = 1; off < 256; off <<= 1) {
        int t = (tid >= off) ? part[tid - off] : 0;
        __syncthreads();
        part[tid] += t;
        __syncthreads();
    }
    int run = part[tid] - sum;  // exclusive prefix
    for (int i = s; i < e; ++i) {
        rowptr[i] = run;
        cursor[i] = run;
        run += deg[i];
    }
    if (tid == 255) rowptr[N] = run;
}

// ---------------- bucket edges into CSR ----------------
__global__ __launch_bounds__(256) void bucket_edges(const int* __restrict__ e0,
                                                    const int* __restrict__ e1,
                                                    int* cursor, int* __restrict__ colIdx, int E) {
    int i = blockIdx.x * 256 + threadIdx.x;
    if (i < E) {
        int r = e0[i];
        int pos = atomicAdd(&cursor[r], 1);
        colIdx[pos] = e1[i];
    }
}

// ---------------- conversions ----------------
__device__ __forceinline__ unsigned short f2bf(float f) {
    unsigned int u = __float_as_uint(f);
    u += 0x7fffu + ((u >> 16) & 1u);
    return (unsigned short)(u >> 16);
}
__device__ __forceinline__ float bfl(unsigned int u) { return __uint_as_float(u << 16); }
__device__ __forceinline__ float bfh(unsigned int u) { return __uint_as_float(u & 0xffff0000u); }
__device__ __forceinline__ unsigned char f2f8(float f) {
    int w = __builtin_amdgcn_cvt_pk_fp8_f32(f, f, 0, false);
    return (unsigned char)(w & 0xff);
}

__global__ __launch_bounds__(256) void to_fp8(const float* __restrict__ src,
                                              unsigned char* __restrict__ dst, int n8) {
    int i = blockIdx.x * 256 + threadIdx.x;  // one thread per 8 floats
    if (i >= n8) return;
    float4 a = ((const float4*)src)[2 * i];
    float4 b = ((const float4*)src)[2 * i + 1];
    int w0 = __builtin_amdgcn_cvt_pk_fp8_f32(a.x, a.y, 0, false);
    w0 = __builtin_amdgcn_cvt_pk_fp8_f32(a.z, a.w, w0, true);
    int w1 = __builtin_amdgcn_cvt_pk_fp8_f32(b.x, b.y, 0, false);
    w1 = __builtin_amdgcn_cvt_pk_fp8_f32(b.z, b.w, w1, true);
    uint2 o;
    o.x = (unsigned int)w0;
    o.y = (unsigned int)w1;
    ((uint2*)dst)[i] = o;
}

// ---------------- W[256][256] fp32 -> Wt[n][k] bf16 ----------------
__global__ __launch_bounds__(256) void transposeW(const float* __restrict__ W,
                                                  unsigned short* __restrict__ Wt) {
    int k = blockIdx.x;
    int n = threadIdx.x;
    Wt[(size_t)n * 256 + k] = f2bf(W[(size_t)k * 256 + n]);
}

// ---------------- Wy[256][64] fp32 -> WyT[64][256] bf16 ----------------
__global__ __launch_bounds__(64) void transposeWy(const float* __restrict__ W,
                                                  unsigned short* __restrict__ Wt) {
    int k = blockIdx.x;   // 0..255
    int n = threadIdx.x;  // 0..63
    Wt[(size_t)n * 256 + k] = f2bf(W[(size_t)k * 64 + n]);
}

// ---------------- MFMA core (shared by both A-type GEMMs); emits fp8 h-table ----------------
__device__ __forceinline__ void gemm_core_f8out(const unsigned short* Al,
                                                const unsigned short* __restrict__ Wt,
                                                unsigned char* __restrict__ out,
                                                int m0, int wv, int lane, int M) {
    f32x4 acc[4][4] = {};
    const int r16 = lane & 15;
    const int kg8 = (lane >> 4) * 8;
    const unsigned short* wbase = Wt + ((size_t)(wv * 64 + r16)) * 256 + kg8;
    const unsigned short* abase = Al + r16 * APAD + kg8;

#pragma unroll
    for (int k0 = 0; k0 < 256; k0 += 32) {
        bf16x8 af[4], bfr[4];
#pragma unroll
        for (int mi = 0; mi < 4; ++mi)
            af[mi] = *(const bf16x8*)&abase[mi * 16 * APAD + k0];
#pragma unroll
        for (int ni = 0; ni < 4; ++ni)
            bfr[ni] = *(const bf16x8*)&wbase[ni * 16 * 256 + k0];
#pragma unroll
        for (int mi = 0; mi < 4; ++mi)
#pragma unroll
            for (int ni = 0; ni < 4; ++ni)
                acc[mi][ni] = __builtin_amdgcn_mfma_f32_16x16x32_bf16(af[mi], bfr[ni], acc[mi][ni], 0, 0, 0);
    }

    // epilogue: C/D layout col=lane&15, row=(lane>>4)*4+j
#pragma unroll
    for (int mi = 0; mi < 4; ++mi) {
        int rbase = m0 + mi * 16 + ((lane >> 4) << 2);
#pragma unroll
        for (int ni = 0; ni < 4; ++ni) {
            int col = (wv << 6) + (ni << 4) + (lane & 15);
#pragma unroll
            for (int j = 0; j < 4; ++j) {
                int row = rbase + j;
                if (row < M) out[(size_t)row * 256 + col] = f2f8(acc[mi][ni][j]);
            }
        }
    }
}

// conv1: A fp32 -> h8 fp8
__global__ __launch_bounds__(256) void gemm_mfma_f32A(const float* __restrict__ A,
                                                      const unsigned short* __restrict__ Wt,
                                                      unsigned char* __restrict__ out, int M) {
    __shared__ unsigned short Al[64 * APAD];
    const int tid = threadIdx.x;
    const int m0 = blockIdx.x * 64;
#pragma unroll
    for (int i = 0; i < 8; ++i) {
        int u = i * 256 + tid;
        int r = u >> 5;
        int c8 = (u & 31) * 8;
        int row = m0 + r;
        float4 v0, v1;
        if (row < M) {
            v0 = *(const float4*)&A[(size_t)row * 256 + c8];
            v1 = *(const float4*)&A[(size_t)row * 256 + c8 + 4];
        } else {
            v0 = make_float4(0.f, 0.f, 0.f, 0.f);
            v1 = v0;
        }
        uint4 o;
        o.x = (unsigned int)f2bf(v0.x) | ((unsigned int)f2bf(v0.y) << 16);
        o.y = (unsigned int)f2bf(v0.z) | ((unsigned int)f2bf(v0.w) << 16);
        o.z = (unsigned int)f2bf(v1.x) | ((unsigned int)f2bf(v1.y) << 16);
        o.w = (unsigned int)f2bf(v1.z) | ((unsigned int)f2bf(v1.w) << 16);
        *(uint4*)&Al[r * APAD + c8] = o;
    }
    __syncthreads();
    gemm_core_f8out(Al, Wt, out, m0, tid >> 6, tid & 63, M);
}

// conv2: A bf16 -> h8 fp8
__global__ __launch_bounds__(256) void gemm_mfma_b16A(const unsigned short* __restrict__ A,
                                                      const unsigned short* __restrict__ Wt,
                                                      unsigned char* __restrict__ out, int M) {
    __shared__ unsigned short Al[64 * APAD];
    const int tid = threadIdx.x;
    const int m0 = blockIdx.x * 64;
#pragma unroll
    for (int i = 0; i < 8; ++i) {
        int u = i * 256 + tid;
        int r = u >> 5;
        int c8 = (u & 31) * 8;
        int row = m0 + r;
        uint4 o = make_uint4(0, 0, 0, 0);
        if (row < M) o = *(const uint4*)&A[(size_t)row * 256 + c8];
        *(uint4*)&Al[r * APAD + c8] = o;
    }
    __syncthreads();
    gemm_core_f8out(Al, Wt, out, m0, tid >> 6, tid & 63, M);
}

// ---------------- MFMA head GEMM: y[M,64] = rep[M,256] @ Wy + by ----------------
__global__ __launch_bounds__(256) void gemm_wy_mfma(const float* __restrict__ A,
                                                    const unsigned short* __restrict__ WyT,
                                                    const float* __restrict__ bias,
                                                    float* __restrict__ out, int M) {
    __shared__ unsigned short Al[64 * APAD];
    const int tid = threadIdx.x;
    const int m0 = blockIdx.x * 64;
    const int wv = tid >> 6;  // wave -> output cols [wv*16, wv*16+16)
    const int lane = tid & 63;

#pragma unroll
    for (int i = 0; i < 8; ++i) {
        int u = i * 256 + tid;
        int r = u >> 5;
        int c8 = (u & 31) * 8;
        int row = m0 + r;
        float4 v0, v1;
        if (row < M) {
            v0 = *(const float4*)&A[(size_t)row * 256 + c8];
            v1 = *(const float4*)&A[(size_t)row * 256 + c8 + 4];
        } else {
            v0 = make_float4(0.f, 0.f, 0.f, 0.f);
            v1 = v0;
        }
        uint4 o;
        o.x = (unsigned int)f2bf(v0.x) | ((unsigned int)f2bf(v0.y) << 16);
        o.y = (unsigned int)f2bf(v0.z) | ((unsigned int)f2bf(v0.w) << 16);
        o.z = (unsigned int)f2bf(v1.x) | ((unsigned int)f2bf(v1.y) << 16);
        o.w = (unsigned int)f2bf(v1.z) | ((unsigned int)f2bf(v1.w) << 16);
        *(uint4*)&Al[r * APAD + c8] = o;
    }
    __syncthreads();

    f32x4 acc[4] = {};
    const int r16 = lane & 15;
    const int kg8 = (lane >> 4) * 8;
    const unsigned short* wbase = WyT + ((size_t)(wv * 16 + r16)) * 256 + kg8;
    const unsigned short* abase = Al + r16 * APAD + kg8;

#pragma unroll
    for (int k0 = 0; k0 < 256; k0 += 32) {
        bf16x8 bfr = *(const bf16x8*)&wbase[k0];
#pragma unroll
        for (int mi = 0; mi < 4; ++mi) {
            bf16x8 af = *(const bf16x8*)&abase[mi * 16 * APAD + k0];
            acc[mi] = __builtin_amdgcn_mfma_f32_16x16x32_bf16(af, bfr, acc[mi], 0, 0, 0);
        }
    }

    int col = (wv << 4) + (lane & 15);
    float bv = bias[col];
#pragma unroll
    for (int mi = 0; mi < 4; ++mi) {
        int rbase = m0 + mi * 16 + ((lane >> 4) << 2);
#pragma unroll
        for (int j = 0; j < 4; ++j) {
            int row = rbase + j;
            if (row < M) out[(size_t)row * 64 + col] = acc[mi][j] + bv;
        }
    }
}

// ---------------- CSR gather SpMM (fp8 h table) fused with finalize; bf16 output ----------------
__global__ __launch_bounds__(256) void spmm_gather_f8(const int* __restrict__ rowptr,
                                                      const int* __restrict__ colIdx,
                                                      const unsigned char* __restrict__ h8,
                                                      const float* __restrict__ dinv,
                                                      const float* __restrict__ bias,
                                                      unsigned short* __restrict__ out,
                                                      int N, int do_relu) {
    int row = (blockIdx.x * 256 + threadIdx.x) >> 6;
    int lane = threadIdx.x & 63;
    if (row >= N) return;
    int beg = rowptr[row];
    int end = rowptr[row + 1];
    float4 acc = make_float4(0.f, 0.f, 0.f, 0.f);
    int j = beg;
    for (; j + 3 < end; j += 4) {
        int c0 = colIdx[j + 0];
        int c1 = colIdx[j + 1];
        int c2 = colIdx[j + 2];
        int c3 = colIdx[j + 3];
        float w0 = dinv[c0], w1 = dinv[c1], w2 = dinv[c2], w3 = dinv[c3];
        unsigned int u0 = *(const unsigned int*)&h8[(size_t)c0 * 256 + lane * 4];
        unsigned int u1 = *(const unsigned int*)&h8[(size_t)c1 * 256 + lane * 4];
        unsigned int u2 = *(const unsigned int*)&h8[(size_t)c2 * 256 + lane * 4];
        unsigned int u3 = *(const unsigned int*)&h8[(size_t)c3 * 256 + lane * 4];
        floatx2 l0 = __builtin_amdgcn_cvt_pk_f32_fp8((int)u0, false);
        floatx2 h0 = __builtin_amdgcn_cvt_pk_f32_fp8((int)u0, true);
        floatx2 l1 = __builtin_amdgcn_cvt_pk_f32_fp8((int)u1, false);
        floatx2 h1 = __builtin_amdgcn_cvt_pk_f32_fp8((int)u1, true);
        floatx2 l2 = __builtin_amdgcn_cvt_pk_f32_fp8((int)u2, false);
        floatx2 h2 = __builtin_amdgcn_cvt_pk_f32_fp8((int)u2, true);
        floatx2 l3 = __builtin_amdgcn_cvt_pk_f32_fp8((int)u3, false);
        floatx2 h3 = __builtin_amdgcn_cvt_pk_f32_fp8((int)u3, true);
        acc.x = fmaf(w0, l0.x, acc.x); acc.y = fmaf(w0, l0.y, acc.y);
        acc.z = fmaf(w0, h0.x, acc.z); acc.w = fmaf(w0, h0.y, acc.w);
        acc.x = fmaf(w1, l1.x, acc.x); acc.y = fmaf(w1, l1.y, acc.y);
        acc.z = fmaf(w1, h1.x, acc.z); acc.w = fmaf(w1, h1.y, acc.w);
        acc.x = fmaf(w2, l2.x, acc.x); acc.y = fmaf(w2, l2.y, acc.y);
        acc.z = fmaf(w2, h2.x, acc.z); acc.w = fmaf(w2, h2.y, acc.w);
        acc.x = fmaf(w3, l3.x, acc.x); acc.y = fmaf(w3, l3.y, acc.y);
        acc.z = fmaf(w3, h3.x, acc.z); acc.w = fmaf(w3, h3.y, acc.w);
    }
    for (; j < end; ++j) {
        int c = colIdx[j];
        float w = dinv[c];
        unsigned int u = *(const unsigned int*)&h8[(size_t)c * 256 + lane * 4];
        floatx2 lo = __builtin_amdgcn_cvt_pk_f32_fp8((int)u, false);
        floatx2 hi = __builtin_amdgcn_cvt_pk_f32_fp8((int)u, true);
        acc.x = fmaf(w, lo.x, acc.x); acc.y = fmaf(w, lo.y, acc.y);
        acc.z = fmaf(w, hi.x, acc.z); acc.w = fmaf(w, hi.y, acc.w);
    }
    float di = dinv[row];
    float s = di * di;
    unsigned int us = *(const unsigned int*)&h8[(size_t)row * 256 + lane * 4];
    floatx2 slo = __builtin_amdgcn_cvt_pk_f32_fp8((int)us, false);
    floatx2 shi = __builtin_amdgcn_cvt_pk_f32_fp8((int)us, true);
    float4 bv = *(const float4*)&bias[lane * 4];
    float4 r;
    r.x = fmaf(di, acc.x, fmaf(s, slo.x, bv.x));
    r.y = fmaf(di, acc.y, fmaf(s, slo.y, bv.y));
    r.z = fmaf(di, acc.z, fmaf(s, shi.x, bv.z));
    r.w = fmaf(di, acc.w, fmaf(s, shi.y, bv.w));
    if (do_relu) {
        r.x = fmaxf(r.x, 0.f);
        r.y = fmaxf(r.y, 0.f);
        r.z = fmaxf(r.z, 0.f);
        r.w = fmaxf(r.w, 0.f);
    }
    uint2 o;
    o.x = (unsigned int)f2bf(r.x) | ((unsigned int)f2bf(r.y) << 16);
    o.y = (unsigned int)f2bf(r.z) | ((unsigned int)f2bf(r.w) << 16);
    *(uint2*)&out[(size_t)row * 256 + lane * 4] = o;
}

// ---------------- double L2 normalize (bf16 in) -> rep fp32 + fp8 table ----------------
__global__ __launch_bounds__(256) void l2norm2_f8(const unsigned short* __restrict__ x2B,
                                                  float* __restrict__ rep,
                                                  unsigned char* __restrict__ rep8, int N) {
    int gw = (blockIdx.x * 256 + threadIdx.x) >> 6;
    int lane = threadIdx.x & 63;
    if (gw >= N) return;
    uint2 u = *(const uint2*)&x2B[(size_t)gw * 256 + lane * 4];
    float4 v = make_float4(bfl(u.x), bfh(u.x), bfl(u.y), bfh(u.y));
    float ss = v.x * v.x + v.y * v.y + v.z * v.z + v.w * v.w;
#pragma unroll
    for (int o = 1; o < 64; o <<= 1) ss += __shfl_xor(ss, o);
    float inv = 1.0f / fmaxf(sqrtf(ss), 1e-12f);
    v.x *= inv; v.y *= inv; v.z *= inv; v.w *= inv;
    float ss2 = v.x * v.x + v.y * v.y + v.z * v.z + v.w * v.w;
#pragma unroll
    for (int o = 1; o < 64; o <<= 1) ss2 += __shfl_xor(ss2, o);
    float inv2 = 1.0f / fmaxf(sqrtf(ss2), 1e-12f);
    v.x *= inv2; v.y *= inv2; v.z *= inv2; v.w *= inv2;
    *(float4*)&rep[(size_t)gw * 256 + lane * 4] = v;
    int w = __builtin_amdgcn_cvt_pk_fp8_f32(v.x, v.y, 0, false);
    w = __builtin_amdgcn_cvt_pk_fp8_f32(v.z, v.w, w, true);
    *(unsigned int*)&rep8[(size_t)gw * 256 + lane * 4] = (unsigned int)w;
}

// ---------------- loss helpers ----------------
__device__ __forceinline__ float dot16fp8(uint4 x, uint4 y) {
    float s = 0.f;
    const unsigned int xs[4] = {x.x, x.y, x.z, x.w};
    const unsigned int ys[4] = {y.x, y.y, y.z, y.w};
#pragma unroll
    for (int i = 0; i < 4; ++i) {
        floatx2 xl = __builtin_amdgcn_cvt_pk_f32_fp8((int)xs[i], false);
        floatx2 xh = __builtin_amdgcn_cvt_pk_f32_fp8((int)xs[i], true);
        floatx2 yl = __builtin_amdgcn_cvt_pk_f32_fp8((int)ys[i], false);
        floatx2 yh = __builtin_amdgcn_cvt_pk_f32_fp8((int)ys[i], true);
        s += xl.x * yl.x + xl.y * yl.y + xh.x * yh.x + xh.y * yh.y;
    }
    return s;
}

// ---------------- reconstruction loss: one edge-pair per 8-lane group (32B/lane) ----------------
__global__ __launch_bounds__(256) void loss_kernel(const int* __restrict__ e0,
                                                   const int* __restrict__ e1,
                                                   const int* __restrict__ n0,
                                                   const int* __restrict__ n1,
                                                   const unsigned char* __restrict__ rep8,
                                                   const unsigned char* __restrict__ feat8,
                                                   const float* __restrict__ ls,
                                                   float* accum, int E) {
    const int tid = threadIdx.x;
    const int l8 = tid & 7;                         // slot within group (32B each)
    const int grp = (blockIdx.x * 256 + tid) >> 3;  // global group id
    const int ngrp = gridDim.x * 32;
    float ap = 0.f, an = 0.f, cp = 0.f, cn = 0.f;
    for (int e = grp; e < E; e += ngrp) {
        int a = e0[e], b = e1[e];
        int c = n0[e], d = n1[e];
        bool dop = a < b;  // uniform within group
        bool don = c < d;
        if (dop) {
            const uint4* pra = (const uint4*)&rep8[(size_t)a * 256 + l8 * 32];
            const uint4* prb = (const uint4*)&rep8[(size_t)b * 256 + l8 * 32];
            const uint4* pfa = (const uint4*)&feat8[(size_t)a * 256 + l8 * 32];
            const uint4* pfb = (const uint4*)&feat8[(size_t)b * 256 + l8 * 32];
            uint4 ra0 = pra[0], ra1 = pra[1];
            uint4 rb0 = prb[0], rb1 = prb[1];
            uint4 fa0 = pfa[0], fa1 = pfa[1];
            uint4 fb0 = pfb[0], fb1 = pfb[1];
            float dp = dot16fp8(ra0, rb0) + dot16fp8(ra1, rb1);
            float df = dot16fp8(fa0, fb0) + dot16fp8(fa1, fb1);
#pragma unroll
            for (int o = 1; o < 8; o <<= 1) {
                dp += __shfl_xor(dp, o);
                df += __shfl_xor(df, o);
            }
            if (l8 == 0) {
                float pw = fmaxf(dp, 0.f);
                float pos = THETA * df + (1.0f - THETA) * pw;
                float t = pos - ls[e];
                ap += t * t;
                cp += 1.f;
            }
        }
        if (don) {
            const uint4* prc = (const uint4*)&rep8[(size_t)c * 256 + l8 * 32];
            const uint4* prd = (const uint4*)&rep8[(size_t)d * 256 + l8 * 32];
            uint4 rc0 = prc[0], rc1 = prc[1];
            uint4 rd0 = prd[0], rd1 = prd[1];
            float dn = dot16fp8(rc0, rd0) + dot16fp8(rc1, rd1);
#pragma unroll
            for (int o = 1; o < 8; o <<= 1) dn += __shfl_xor(dn, o);
            if (l8 == 0) {
                float nwt = fmaxf(dn, 0.f);
                an += nwt * nwt;
                cn += 1.f;
            }
        }
    }
    // wave-level reduce (partials live on lanes with l8==0; others are 0)
#pragma unroll
    for (int o = 1; o < 64; o <<= 1) {
        ap += __shfl_xor(ap, o);
        an += __shfl_xor(an, o);
        cp += __shfl_xor(cp, o);
        cn += __shfl_xor(cn, o);
    }
    __shared__ float s[4][4];
    const int wline = tid >> 6;
    if ((tid & 63) == 0) {
        s[wline][0] = ap;
        s[wline][1] = an;
        s[wline][2] = cp;
        s[wline][3] = cn;
    }
    __syncthreads();
    if (tid == 0) {
        float tp = 0.f, tn = 0.f, tcp = 0.f, tcn = 0.f;
#pragma unroll
        for (int w = 0; w < 4; ++w) {
            tp += s[w][0];
            tn += s[w][1];
            tcp += s[w][2];
            tcn += s[w][3];
        }
        unsafeAtomicAdd(&accum[0], tp);
        unsafeAtomicAdd(&accum[1], tn);
        unsafeAtomicAdd(&accum[2], tcp);
        unsafeAtomicAdd(&accum[3], tcn);
    }
}

__global__ void loss_final(const float* __restrict__ accum, float* __restrict__ out, int N) {
    out[0] = (accum[1] + accum[0]) * (float)N / (accum[3] + accum[2]);
}

// ---------------- launcher ----------------
extern "C" void kernel_launch(void* const* d_in, const int* in_sizes, int n_in,
                              void* d_out, int out_size, void* d_ws, size_t ws_size,
                              hipStream_t stream) {
    const int* edge = (const int*)d_in[0];
    const float* features = (const float*)d_in[1];
    const float* ls = (const float*)d_in[2];
    const int* nedge = (const int*)d_in[3];
    const float* W1 = (const float*)d_in[4];
    const float* b1 = (const float*)d_in[5];
    const float* W2 = (const float*)d_in[6];
    const float* b2 = (const float*)d_in[7];
    const float* Wy = (const float*)d_in[8];
    const float* by = (const float*)d_in[9];

    const int E = in_sizes[0] / 2;
    const int N = in_sizes[1] / FEAT;
    const int* e0 = edge;
    const int* e1 = edge + E;
    const int* n0 = nedge;
    const int* n1 = nedge + E;

    float* rep = (float*)d_out;          // [N,256]
    float* rec = rep + (size_t)N * 256;  // scalar
    float* y = rec + 1;                  // [N,64], 4B-aligned only

    // workspace carve-out
    char* base = (char*)d_ws;
    size_t off = 0;
    auto carve = [&](size_t bytes) -> void* {
        void* p = base + off;
        off += (bytes + 1023) & ~(size_t)1023;
        return p;
    };
    int* deg = (int*)carve((size_t)N * 4);
    float* dinv = (float*)carve((size_t)N * 4);
    float* accum = (float*)carve(16);
    int* rowptr = (int*)carve((size_t)(N + 1) * 4);
    int* cursor = (int*)carve((size_t)N * 4);
    int* colIdx = (int*)carve((size_t)E * 4);
    unsigned char* h8 = (unsigned char*)carve((size_t)N * 256);         // fp8 h table
    unsigned short* x1B = (unsigned short*)carve((size_t)N * 256 * 2);  // bf16 x1
    unsigned short* x2B = (unsigned short*)carve((size_t)N * 256 * 2);  // bf16 x2
    unsigned char* feat8 = (unsigned char*)carve((size_t)N * 256);
    unsigned char* rep8 = (unsigned char*)carve((size_t)N * 256);
    unsigned short* Wt1 = (unsigned short*)carve(256 * 256 * 2);
    unsigned short* Wt2 = (unsigned short*)carve(256 * 256 * 2);
    unsigned short* WyT = (unsigned short*)carve(64 * 256 * 2);

    // CSR build
    hipMemsetAsync(deg, 0, (size_t)N * 4, stream);
    deg_count<<<(E + 255) / 256, 256, 0, stream>>>(e0, E, deg);
    make_dinv<<<(N + 255) / 256, 256, 0, stream>>>(deg, dinv, N);
    scan_rowptr<<<1, 256, 0, stream>>>(deg, rowptr, cursor, N);
    bucket_edges<<<(E + 255) / 256, 256, 0, stream>>>(e0, e1, cursor, colIdx, E);

    const int gblk = (N + 63) / 64;
    const int wblk = (N + 3) / 4;
    const int n8 = N * 256 / 8;

    // loss-side fp8 feature table; bf16-transposed weights
    to_fp8<<<(n8 + 255) / 256, 256, 0, stream>>>(features, feat8, n8);
    transposeW<<<256, 256, 0, stream>>>(W1, Wt1);
    transposeW<<<256, 256, 0, stream>>>(W2, Wt2);
    transposeWy<<<256, 64, 0, stream>>>(Wy, WyT);

    // conv1: h8 = fp8(features @ W1); x1B = bf16(relu(gather + selfloop + b1))
    gemm_mfma_f32A<<<gblk, 256, 0, stream>>>(features, Wt1, h8, N);
    spmm_gather_f8<<<wblk, 256, 0, stream>>>(rowptr, colIdx, h8, dinv, b1, x1B, N, 1);

    // conv2: h8 = fp8(x1B @ W2); x2B = bf16(gather + selfloop + b2)
    gemm_mfma_b16A<<<gblk, 256, 0, stream>>>(x1B, Wt2, h8, N);
    spmm_gather_f8<<<wblk, 256, 0, stream>>>(rowptr, colIdx, h8, dinv, b2, x2B, N, 0);

    // rep = l2norm(l2norm(x2)) -> fp32 rep + fp8 table
    l2norm2_f8<<<wblk, 256, 0, stream>>>(x2B, rep, rep8, N);

    // y = rep @ Wy + by (MFMA)
    gemm_wy_mfma<<<gblk, 256, 0, stream>>>(rep, WyT, by, y, N);

    // loss
    hipMemsetAsync(accum, 0, 16, stream);
    loss_kernel<<<2048, 256, 0, stream>>>(e0, e1, n0, n1, rep8, feat8, ls, accum, E);
    loss_final<<<1, 1, 0, stream>>>(accum, rec, N);
}